// Round 1
// baseline (463.851 us; speedup 1.0000x reference)
//
#include <hip/hip_runtime.h>
#include <hip/hip_bf16.h>

#define DEVI static __device__ __forceinline__

typedef __attribute__((ext_vector_type(4))) float f32x4;
typedef __attribute__((ext_vector_type(8))) short bf16x8;
typedef __attribute__((ext_vector_type(4))) short s16x4;

constexpr int TB  = 2;      // batch
constexpr int TS  = 2048;   // seq len
constexpr int TD  = 1024;   // model dim
constexpr int TH  = 16;     // heads
constexpr int TDH = 64;     // head dim
constexpr int TC  = 64;     // window size
constexpr int TFF = 4096;   // ffn dim

DEVI float bf2f(short s) {
  return __builtin_bit_cast(float, (unsigned)((unsigned short)s) << 16);
}
DEVI short f2bf(float f) {
  return __builtin_bit_cast(short, __float2bfloat16(f));
}

// ---------------- weight transpose + f32->bf16 convert --------------------
// W (K x N) f32 row-major  ->  WT (N x K) bf16 row-major
__global__ __launch_bounds__(256) void k_transpose_bf16(
    const float* __restrict__ W, __hip_bfloat16* __restrict__ WT, int K, int N) {
  __shared__ float tile[32][33];
  int n0 = blockIdx.x * 32, k0 = blockIdx.y * 32;
  int tx = threadIdx.x & 31, ty = threadIdx.x >> 5;  // 32 x 8
  for (int i = 0; i < 32; i += 8)
    tile[ty + i][tx] = W[(size_t)(k0 + ty + i) * N + n0 + tx];
  __syncthreads();
  for (int i = 0; i < 32; i += 8)
    WT[(size_t)(n0 + ty + i) * K + k0 + tx] = __float2bfloat16(tile[tx][ty + i]);
}

// ---------------- h = x + pos[t % C] --------------------------------------
__global__ __launch_bounds__(256) void k_addpos(
    const float* __restrict__ x, const float* __restrict__ pos,
    float* __restrict__ hf, __hip_bfloat16* __restrict__ hb, int total4) {
  int i = blockIdx.x * 256 + threadIdx.x;
  if (i >= total4) return;
  int e = i * 4;
  int d = e & (TD - 1);
  int t = (e / TD) & (TS - 1);
  f32x4 xv = *(const f32x4*)(x + e);
  f32x4 pv = *(const f32x4*)(pos + (size_t)(t & (TC - 1)) * TD + d);
  f32x4 h = xv + pv;
  *(f32x4*)(hf + e) = h;
  s16x4 hb4;
  for (int j = 0; j < 4; j++) hb4[j] = f2bf(h[j]);
  *(s16x4*)((short*)hb + e) = hb4;
}

// ---------------- bf16 MFMA GEMM: C = A(MxK) * BT(NxK)^T ------------------
// EPI: 0 = store bf16, 1 = bias+relu -> bf16, 2 = store f32
template <int EPI>
__global__ __launch_bounds__(256) void k_gemm(
    const __hip_bfloat16* __restrict__ A, const __hip_bfloat16* __restrict__ BT,
    void* __restrict__ Cout, const float* __restrict__ bias, int M, int N, int K) {
  constexpr int BM = 128, BN = 128, BK = 32;
  __shared__ __align__(16) __hip_bfloat16 As[BM][BK + 8];  // stride 80B, 16B-aligned
  __shared__ __align__(16) __hip_bfloat16 Bs[BN][BK + 8];
  int m0 = blockIdx.x * BM, n0 = blockIdx.y * BN;
  int tid = threadIdx.x;
  int lane = tid & 63, wave = tid >> 6;
  int wm = wave >> 1, wn = wave & 1;   // 2x2 wave grid, 64x64 per wave
  int fr = lane & 15, fg = lane >> 4;  // fragment row/col + k-octet
  f32x4 acc[4][4] = {};
  for (int k0 = 0; k0 < K; k0 += BK) {
    for (int c = tid; c < BM * BK / 8; c += 256) {  // 512 16B chunks each for A,B
      int row = c >> 2, seg = c & 3;
      bf16x8 vA = *(const bf16x8*)(A + (size_t)(m0 + row) * K + k0 + seg * 8);
      *(bf16x8*)(&As[row][seg * 8]) = vA;
      bf16x8 vB = *(const bf16x8*)(BT + (size_t)(n0 + row) * K + k0 + seg * 8);
      *(bf16x8*)(&Bs[row][seg * 8]) = vB;
    }
    __syncthreads();
    bf16x8 af[4], bfr[4];
    for (int m = 0; m < 4; m++) af[m]  = *(const bf16x8*)(&As[wm * 64 + m * 16 + fr][fg * 8]);
    for (int n = 0; n < 4; n++) bfr[n] = *(const bf16x8*)(&Bs[wn * 64 + n * 16 + fr][fg * 8]);
    for (int m = 0; m < 4; m++)
      for (int n = 0; n < 4; n++)
        acc[m][n] = __builtin_amdgcn_mfma_f32_16x16x32_bf16(af[m], bfr[n], acc[m][n], 0, 0, 0);
    __syncthreads();
  }
  for (int m = 0; m < 4; m++)
    for (int n = 0; n < 4; n++) {
      int col = n0 + wn * 64 + n * 16 + fr;
      for (int j = 0; j < 4; j++) {
        int row = m0 + wm * 64 + m * 16 + fg * 4 + j;
        float v = acc[m][n][j];
        if (EPI == 1) { v += bias[col]; v = fmaxf(v, 0.f); }
        if (EPI == 2)
          ((float*)Cout)[(size_t)row * N + col] = v;
        else
          ((__hip_bfloat16*)Cout)[(size_t)row * N + col] = __float2bfloat16(v);
      }
    }
}

// ---------------- sliding-window attention --------------------------------
// one wave per (b,h,t); lane j handles diagonal d=j (T = t-j)
__global__ __launch_bounds__(256) void k_attn(
    const __hip_bfloat16* __restrict__ q, const __hip_bfloat16* __restrict__ k,
    const __hip_bfloat16* __restrict__ v, const float* __restrict__ rpe,
    __hip_bfloat16* __restrict__ out) {
  __shared__ float q_lds[4][TDH];
  __shared__ float p_lds[4][64];
  int wave = threadIdx.x >> 6, lane = threadIdx.x & 63;
  int idx = blockIdx.x * 4 + wave;        // (b*H + h)*S + t
  int t = idx & (TS - 1);
  int bh = idx >> 11;
  int h = bh & (TH - 1);
  int b = bh >> 4;
  size_t rowbase = ((size_t)b * TS + t) * (TH * TDH) + h * TDH;
  q_lds[wave][lane] = bf2f(((const short*)q)[rowbase + lane]);
  __syncthreads();
  int T = t - lane;
  int Tc = T < 0 ? 0 : T;
  size_t krow = ((size_t)b * TS + Tc) * TD + h * TDH;
  float s = 0.f;
  for (int d0 = 0; d0 < TDH; d0 += 8) {
    bf16x8 kv = *(const bf16x8*)(k + krow + d0);
    for (int j = 0; j < 8; j++) s += q_lds[wave][d0 + j] * bf2f(kv[j]);
  }
  s = s * 0.125f + rpe[h * TC + lane];
  if (T < 0) s = -3.4028235e38f;
  float m = s;
  for (int o = 32; o; o >>= 1) m = fmaxf(m, __shfl_xor(m, o));
  float p = __expf(s - m);
  float sum = p;
  for (int o = 32; o; o >>= 1) sum += __shfl_xor(sum, o);
  p /= sum;
  p_lds[wave][lane] = p;
  __syncthreads();
  int jmax = t < 63 ? t : 63;
  float o = 0.f;
  for (int j = 0; j <= jmax; j++) {
    size_t vrow = ((size_t)b * TS + (t - j)) * TD + h * TDH;
    o += p_lds[wave][j] * bf2f(((const short*)v)[vrow + lane]);
  }
  ((short*)out)[rowbase + lane] = f2bf(o);
}

// ---------------- LayerNorm (two-pass, fused residual) --------------------
DEVI float block_sum(float v, float* red) {
  for (int o = 32; o; o >>= 1) v += __shfl_xor(v, o);
  int wave = threadIdx.x >> 6;
  if ((threadIdx.x & 63) == 0) red[wave] = v;
  __syncthreads();
  float r = red[0] + red[1] + red[2] + red[3];
  __syncthreads();
  return r;
}

// MODE 0: in = A+Bm,       write f32 + bf16 (ln1)
// MODE 1: in = A+Bm+bias,  write f32 only   (ln2 -> d_out)
template <int MODE>
__global__ __launch_bounds__(256) void k_ln(
    const float* __restrict__ A, const float* __restrict__ Bm,
    const float* __restrict__ bias, const float* __restrict__ scale,
    const float* __restrict__ offset, float* __restrict__ outf,
    __hip_bfloat16* __restrict__ outb) {
  __shared__ float red[4];
  int row = blockIdx.x, tid = threadIdx.x;
  size_t base = (size_t)row * TD + tid * 4;
  f32x4 xa = *(const f32x4*)(A + base);
  f32x4 xb = *(const f32x4*)(Bm + base);
  f32x4 xv = xa + xb;
  if (MODE == 1) {
    f32x4 bi = *(const f32x4*)(bias + tid * 4);
    xv = xv + bi;
  }
  float s = xv[0] + xv[1] + xv[2] + xv[3];
  s = block_sum(s, red);
  float mu = s * (1.f / TD);
  float s2 = 0.f;
  for (int j = 0; j < 4; j++) { float dlt = xv[j] - mu; s2 += dlt * dlt; }
  s2 = block_sum(s2, red);
  float rs = rsqrtf(s2 * (1.f / TD) + 1e-5f);
  f32x4 sc = *(const f32x4*)(scale + tid * 4);
  f32x4 of = *(const f32x4*)(offset + tid * 4);
  f32x4 y;
  for (int j = 0; j < 4; j++) y[j] = (xv[j] - mu) * rs * sc[j] + of[j];
  *(f32x4*)(outf + base) = y;
  if (MODE == 0) {
    s16x4 pb;
    for (int j = 0; j < 4; j++) pb[j] = f2bf(y[j]);
    *(s16x4*)((short*)outb + base) = pb;
  }
}

// --------------------------------------------------------------------------
extern "C" void kernel_launch(void* const* d_in, const int* in_sizes, int n_in,
                              void* d_out, int out_size, void* d_ws, size_t ws_size,
                              hipStream_t stream) {
  const float* x    = (const float*)d_in[0];
  // d_in[1] = causal_mask (unused; window mask subsumes it)
  const float* pos  = (const float*)d_in[2];
  const float* rpe  = (const float*)d_in[3];
  const float* Wq   = (const float*)d_in[4];
  const float* Wk   = (const float*)d_in[5];
  const float* Wv   = (const float*)d_in[6];
  const float* Wo   = (const float*)d_in[7];
  const float* ln1s = (const float*)d_in[8];
  const float* ln1o = (const float*)d_in[9];
  const float* W1   = (const float*)d_in[10];
  const float* b1   = (const float*)d_in[11];
  const float* W2   = (const float*)d_in[12];
  const float* b2   = (const float*)d_in[13];
  const float* ln2s = (const float*)d_in[14];
  const float* ln2o = (const float*)d_in[15];

  char* ws = (char*)d_ws;
  const size_t MB = 1ull << 20;
  __hip_bfloat16* WqT = (__hip_bfloat16*)(ws + 0 * MB);    // 2 MB
  __hip_bfloat16* WkT = (__hip_bfloat16*)(ws + 2 * MB);    // 2 MB
  __hip_bfloat16* WvT = (__hip_bfloat16*)(ws + 4 * MB);    // 2 MB
  __hip_bfloat16* WoT = (__hip_bfloat16*)(ws + 6 * MB);    // 2 MB
  __hip_bfloat16* W1T = (__hip_bfloat16*)(ws + 8 * MB);    // 8 MB
  __hip_bfloat16* W2T = (__hip_bfloat16*)(ws + 16 * MB);   // 8 MB
  float*          hF  = (float*)(ws + 24 * MB);            // 16 MB
  __hip_bfloat16* hB  = (__hip_bfloat16*)(ws + 40 * MB);   // 8 MB
  __hip_bfloat16* qB  = (__hip_bfloat16*)(ws + 48 * MB);   // 8 MB
  __hip_bfloat16* kB  = (__hip_bfloat16*)(ws + 56 * MB);   // 8 MB
  __hip_bfloat16* vB  = (__hip_bfloat16*)(ws + 64 * MB);   // 8 MB
  __hip_bfloat16* aoB = (__hip_bfloat16*)(ws + 72 * MB);   // 8 MB
  float*          oF  = (float*)(ws + 80 * MB);            // 16 MB
  float*          atF = (float*)(ws + 96 * MB);            // 16 MB
  __hip_bfloat16* atB = (__hip_bfloat16*)(ws + 112 * MB);  // 8 MB
  __hip_bfloat16* ff1 = (__hip_bfloat16*)(ws + 48 * MB);   // 32 MB (aliases q/k/v/ao, dead)
  float*          ff2 = (float*)(ws + 80 * MB);            // 16 MB (aliases oF, dead)

  const int M = TB * TS;  // 4096
  dim3 blk(256);

  k_transpose_bf16<<<dim3(TD / 32, TD / 32), blk, 0, stream>>>(Wq, WqT, TD, TD);
  k_transpose_bf16<<<dim3(TD / 32, TD / 32), blk, 0, stream>>>(Wk, WkT, TD, TD);
  k_transpose_bf16<<<dim3(TD / 32, TD / 32), blk, 0, stream>>>(Wv, WvT, TD, TD);
  k_transpose_bf16<<<dim3(TD / 32, TD / 32), blk, 0, stream>>>(Wo, WoT, TD, TD);
  k_transpose_bf16<<<dim3(TFF / 32, TD / 32), blk, 0, stream>>>(W1, W1T, TD, TFF);
  k_transpose_bf16<<<dim3(TD / 32, TFF / 32), blk, 0, stream>>>(W2, W2T, TFF, TD);

  k_addpos<<<(M * TD / 4 + 255) / 256, blk, 0, stream>>>(x, pos, hF, hB, M * TD / 4);

  k_gemm<0><<<dim3(M / 128, TD / 128), blk, 0, stream>>>(hB, WqT, qB, nullptr, M, TD, TD);
  k_gemm<0><<<dim3(M / 128, TD / 128), blk, 0, stream>>>(hB, WkT, kB, nullptr, M, TD, TD);
  k_gemm<0><<<dim3(M / 128, TD / 128), blk, 0, stream>>>(hB, WvT, vB, nullptr, M, TD, TD);

  k_attn<<<TB * TH * TS / 4, blk, 0, stream>>>(qB, kB, vB, rpe, aoB);

  k_gemm<2><<<dim3(M / 128, TD / 128), blk, 0, stream>>>(aoB, WoT, oF, nullptr, M, TD, TD);

  k_ln<0><<<M, blk, 0, stream>>>(hF, oF, nullptr, ln1s, ln1o, atF, atB);

  k_gemm<1><<<dim3(M / 128, TFF / 128), blk, 0, stream>>>(atB, W1T, ff1, b1, M, TFF, TD);
  k_gemm<2><<<dim3(M / 128, TD / 128), blk, 0, stream>>>(ff1, W2T, ff2, nullptr, M, TD, TFF);

  k_ln<1><<<M, blk, 0, stream>>>(ff2, atF, b2, ln2s, ln2o, (float*)d_out, nullptr);
}

// Round 2
// 330.498 us; speedup vs baseline: 1.4035x; 1.4035x over previous
//
#include <hip/hip_runtime.h>
#include <hip/hip_bf16.h>

#define DEVI static __device__ __forceinline__

typedef __attribute__((ext_vector_type(4))) float f32x4;
typedef __attribute__((ext_vector_type(8))) short bf16x8;
typedef __attribute__((ext_vector_type(4))) short s16x4;

constexpr int TB  = 2;      // batch
constexpr int TS  = 2048;   // seq len
constexpr int TD  = 1024;   // model dim
constexpr int TH  = 16;     // heads
constexpr int TDH = 64;     // head dim
constexpr int TC  = 64;     // window size
constexpr int TFF = 4096;   // ffn dim
constexpr int TM  = TB * TS;  // 4096 rows

DEVI float bf2f(short s) {
  return __builtin_bit_cast(float, (unsigned)((unsigned short)s) << 16);
}
DEVI short f2bf(float f) {
  return __builtin_bit_cast(short, __float2bfloat16(f));
}

// async global->LDS, 16B per lane, dest = wave-uniform base + lane*16
#define GLD16(gp, lp)                                              \
  __builtin_amdgcn_global_load_lds(                                \
      (const __attribute__((address_space(1))) void*)(gp),         \
      (__attribute__((address_space(3))) void*)(lp), 16, 0, 0)

// ---------------- weight transpose + f32->bf16 convert --------------------
// W (K x N) f32 row-major  ->  WT (N x K) bf16 row-major
__global__ __launch_bounds__(256) void k_transpose_bf16(
    const float* __restrict__ W, __hip_bfloat16* __restrict__ WT, int K, int N) {
  __shared__ float tile[32][33];
  int n0 = blockIdx.x * 32, k0 = blockIdx.y * 32;
  int tx = threadIdx.x & 31, ty = threadIdx.x >> 5;  // 32 x 8
  for (int i = 0; i < 32; i += 8)
    tile[ty + i][tx] = W[(size_t)(k0 + ty + i) * N + n0 + tx];
  __syncthreads();
  for (int i = 0; i < 32; i += 8)
    WT[(size_t)(n0 + ty + i) * K + k0 + tx] = __float2bfloat16(tile[tx][ty + i]);
}

// ---------------- h = x + pos[t % C] (bf16 only) --------------------------
__global__ __launch_bounds__(256) void k_addpos(
    const float* __restrict__ x, const float* __restrict__ pos,
    __hip_bfloat16* __restrict__ hb, int total4) {
  int i = blockIdx.x * 256 + threadIdx.x;
  if (i >= total4) return;
  int e = i * 4;
  int d = e & (TD - 1);
  int t = (e / TD) & (TS - 1);
  f32x4 xv = *(const f32x4*)(x + e);
  f32x4 pv = *(const f32x4*)(pos + (size_t)(t & (TC - 1)) * TD + d);
  s16x4 hb4;
  for (int j = 0; j < 4; j++) hb4[j] = f2bf(xv[j] + pv[j]);
  *(s16x4*)((short*)hb + e) = hb4;
}

// ---------------- bf16 MFMA GEMM (m97-style + 2-phase dbuf) ---------------
// C = A(MxK) * BT(NxK)^T.  BM=BN=128, BK=32, 256 thr (4 waves, 2x2),
// global_load_lds width-16 into linear LDS; source pre-swizzled so
// ds_read_b128 with slot^=(row&3) is bank-uniform (rule 21 pattern).
// split-K via blockIdx.z: A/BT advanced by z*K, f32 partial per z.
// EPI: 0 = store bf16, 1 = bias+relu -> bf16, 2 = store f32 (partials)
template <int EPI>
__global__ __launch_bounds__(256) void k_gemm(
    const __hip_bfloat16* __restrict__ A, const __hip_bfloat16* __restrict__ BT,
    void* __restrict__ Cout, const float* __restrict__ bias,
    int M, int N, int K, int lda, int ldb) {
  constexpr int BM = 128, BN = 128, BK = 32;
  __shared__ __align__(16) __hip_bfloat16 As[2][BM * BK];  // 8 KB per buf
  __shared__ __align__(16) __hip_bfloat16 Bs[2][BN * BK];
  int tid = threadIdx.x;
  int lane = tid & 63, wave = tid >> 6;
  int wm = wave >> 1, wn = wave & 1;   // 2x2 wave grid, 64x64 per wave
  int fr = lane & 15, fg = lane >> 4;  // fragment row + k-octet
  int m0 = blockIdx.x * BM, n0 = blockIdx.y * BN;
  size_t koff = (size_t)blockIdx.z * K;
  const __hip_bfloat16* Ab = A + koff;
  const __hip_bfloat16* Bb = BT + koff;

  // stage tile k0 into buffer s: 512 chunks of 16B each for A and B;
  // chunk c holds global (row=c>>2, seg=(c&3)^(row&3))  [inverse swizzle]
  auto stage = [&](int s, int k0) {
#pragma unroll
    for (int i = 0; i < 2; i++) {
      int c = (wave * 2 + i) * 64 + lane;
      int row = c >> 2, seg = (c & 3) ^ (row & 3);
      GLD16(Ab + (size_t)(m0 + row) * lda + k0 + seg * 8,
            (char*)&As[s][0] + (wave * 2 + i) * 1024);
      GLD16(Bb + (size_t)(n0 + row) * ldb + k0 + seg * 8,
            (char*)&Bs[s][0] + (wave * 2 + i) * 1024);
    }
  };

  f32x4 acc[4][4] = {};
  const int nt = K / BK;
  stage(0, 0);
  __syncthreads();  // vmcnt(0) drain + barrier
  for (int t = 0; t < nt; t++) {
    int cur = t & 1;
    if (t + 1 < nt) stage(cur ^ 1, (t + 1) * BK);  // prefetch overlaps MFMA
    bf16x8 af[4], bfv[4];
#pragma unroll
    for (int m = 0; m < 4; m++) {
      int row = wm * 64 + m * 16 + fr;
      af[m] = *(const bf16x8*)((const char*)&As[cur][0] + row * 64 +
                               ((fg ^ (row & 3)) * 16));
    }
#pragma unroll
    for (int n = 0; n < 4; n++) {
      int row = wn * 64 + n * 16 + fr;
      bfv[n] = *(const bf16x8*)((const char*)&Bs[cur][0] + row * 64 +
                                ((fg ^ (row & 3)) * 16));
    }
#pragma unroll
    for (int m = 0; m < 4; m++)
#pragma unroll
      for (int n = 0; n < 4; n++)
        acc[m][n] = __builtin_amdgcn_mfma_f32_16x16x32_bf16(af[m], bfv[n],
                                                            acc[m][n], 0, 0, 0);
    __syncthreads();  // one barrier per K-tile (drains this tile's prefetch)
  }

  float* Cf = (float*)Cout + (size_t)blockIdx.z * M * N;
#pragma unroll
  for (int m = 0; m < 4; m++)
#pragma unroll
    for (int n = 0; n < 4; n++) {
      int col = n0 + wn * 64 + n * 16 + fr;
#pragma unroll
      for (int j = 0; j < 4; j++) {
        int row = m0 + wm * 64 + m * 16 + fg * 4 + j;
        float v = acc[m][n][j];
        if (EPI == 1) { v += bias[col]; v = fmaxf(v, 0.f); }
        if (EPI == 2)
          Cf[(size_t)row * N + col] = v;
        else
          ((__hip_bfloat16*)Cout)[(size_t)row * N + col] = __float2bfloat16(v);
      }
    }
}

// ---------------- sliding-window attention --------------------------------
// one wave per (b,h,t); lane j handles diagonal d=j (T = t-j)
// q/k/v live fused in qkv (row stride 3072; offsets 0/1024/2048)
__global__ __launch_bounds__(256) void k_attn(
    const __hip_bfloat16* __restrict__ qkv, const float* __restrict__ rpe,
    __hip_bfloat16* __restrict__ out) {
  __shared__ float q_lds[4][TDH];
  __shared__ float p_lds[4][64];
  int wave = threadIdx.x >> 6, lane = threadIdx.x & 63;
  int idx = blockIdx.x * 4 + wave;  // (b*H + h)*S + t
  int t = idx & (TS - 1);
  int bh = idx >> 11;
  int h = bh & (TH - 1);
  int b = bh >> 4;
  size_t qrow = ((size_t)b * TS + t) * 3072 + h * TDH;
  q_lds[wave][lane] = bf2f(((const short*)qkv)[qrow + lane]);
  __syncthreads();
  int T = t - lane;
  int Tc = T < 0 ? 0 : T;
  size_t krow = ((size_t)b * TS + Tc) * 3072 + 1024 + h * TDH;
  float s = 0.f;
  for (int d0 = 0; d0 < TDH; d0 += 8) {
    bf16x8 kv = *(const bf16x8*)((const short*)qkv + krow + d0);
    for (int j = 0; j < 8; j++) s += q_lds[wave][d0 + j] * bf2f(kv[j]);
  }
  s = s * 0.125f + rpe[h * TC + lane];
  if (T < 0) s = -3.4028235e38f;
  float m = s;
  for (int o = 32; o; o >>= 1) m = fmaxf(m, __shfl_xor(m, o));
  float p = __expf(s - m);
  float sum = p;
  for (int o = 32; o; o >>= 1) sum += __shfl_xor(sum, o);
  p /= sum;
  p_lds[wave][lane] = p;
  __syncthreads();
  int jmax = t < 63 ? t : 63;
  float o = 0.f;
  for (int j = 0; j <= jmax; j++) {
    size_t vrow = ((size_t)b * TS + (t - j)) * 3072 + 2048 + h * TDH;
    o += p_lds[wave][j] * bf2f(((const short*)qkv)[vrow + lane]);
  }
  ((short*)out)[((size_t)b * TS + t) * TD + h * TDH + lane] = f2bf(o);
}

// ---------------- LayerNorm (two-pass, fused residual + split-K sum) ------
DEVI float block_sum(float v, float* red) {
  for (int o = 32; o; o >>= 1) v += __shfl_xor(v, o);
  int wave = threadIdx.x >> 6;
  if ((threadIdx.x & 63) == 0) red[wave] = v;
  __syncthreads();
  float r = red[0] + red[1] + red[2] + red[3];
  __syncthreads();
  return r;
}

// ln1: in = (x + pos[t%C]) + P0 + P1, write f32 + bf16
__global__ __launch_bounds__(256) void k_ln1(
    const float* __restrict__ x, const float* __restrict__ pos,
    const float* __restrict__ P0, const float* __restrict__ P1,
    const float* __restrict__ scale, const float* __restrict__ offset,
    float* __restrict__ outf, __hip_bfloat16* __restrict__ outb) {
  __shared__ float red[4];
  int row = blockIdx.x, tid = threadIdx.x;
  int t = row & (TS - 1), pr = t & (TC - 1);
  size_t base = (size_t)row * TD + tid * 4;
  f32x4 xv = *(const f32x4*)(x + base);
  f32x4 pv = *(const f32x4*)(pos + (size_t)pr * TD + tid * 4);
  f32x4 a0 = *(const f32x4*)(P0 + base);
  f32x4 a1 = *(const f32x4*)(P1 + base);
  xv = xv + pv + a0 + a1;
  float s = xv[0] + xv[1] + xv[2] + xv[3];
  s = block_sum(s, red);
  float mu = s * (1.f / TD);
  float s2 = 0.f;
  for (int j = 0; j < 4; j++) { float dlt = xv[j] - mu; s2 += dlt * dlt; }
  s2 = block_sum(s2, red);
  float rs = rsqrtf(s2 * (1.f / TD) + 1e-5f);
  f32x4 sc = *(const f32x4*)(scale + tid * 4);
  f32x4 of = *(const f32x4*)(offset + tid * 4);
  f32x4 y;
  for (int j = 0; j < 4; j++) y[j] = (xv[j] - mu) * rs * sc[j] + of[j];
  *(f32x4*)(outf + base) = y;
  s16x4 pb;
  for (int j = 0; j < 4; j++) pb[j] = f2bf(y[j]);
  *(s16x4*)((short*)outb + base) = pb;
}

// ln2: in = P0 + P1 + R + bias, write f32 (d_out)
__global__ __launch_bounds__(256) void k_ln2(
    const float* __restrict__ P0, const float* __restrict__ P1,
    const float* __restrict__ R, const float* __restrict__ bias,
    const float* __restrict__ scale, const float* __restrict__ offset,
    float* __restrict__ outf) {
  __shared__ float red[4];
  int row = blockIdx.x, tid = threadIdx.x;
  size_t base = (size_t)row * TD + tid * 4;
  f32x4 a0 = *(const f32x4*)(P0 + base);
  f32x4 a1 = *(const f32x4*)(P1 + base);
  f32x4 rv = *(const f32x4*)(R + base);
  f32x4 bi = *(const f32x4*)(bias + tid * 4);
  f32x4 xv = a0 + a1 + rv + bi;
  float s = xv[0] + xv[1] + xv[2] + xv[3];
  s = block_sum(s, red);
  float mu = s * (1.f / TD);
  float s2 = 0.f;
  for (int j = 0; j < 4; j++) { float dlt = xv[j] - mu; s2 += dlt * dlt; }
  s2 = block_sum(s2, red);
  float rs = rsqrtf(s2 * (1.f / TD) + 1e-5f);
  f32x4 sc = *(const f32x4*)(scale + tid * 4);
  f32x4 of = *(const f32x4*)(offset + tid * 4);
  f32x4 y;
  for (int j = 0; j < 4; j++) y[j] = (xv[j] - mu) * rs * sc[j] + of[j];
  *(f32x4*)(outf + base) = y;
}

// --------------------------------------------------------------------------
extern "C" void kernel_launch(void* const* d_in, const int* in_sizes, int n_in,
                              void* d_out, int out_size, void* d_ws, size_t ws_size,
                              hipStream_t stream) {
  const float* x    = (const float*)d_in[0];
  // d_in[1] = causal_mask (unused; window mask subsumes it)
  const float* pos  = (const float*)d_in[2];
  const float* rpe  = (const float*)d_in[3];
  const float* Wq   = (const float*)d_in[4];
  const float* Wk   = (const float*)d_in[5];
  const float* Wv   = (const float*)d_in[6];
  const float* Wo   = (const float*)d_in[7];
  const float* ln1s = (const float*)d_in[8];
  const float* ln1o = (const float*)d_in[9];
  const float* W1   = (const float*)d_in[10];
  const float* b1   = (const float*)d_in[11];
  const float* W2   = (const float*)d_in[12];
  const float* b2   = (const float*)d_in[13];
  const float* ln2s = (const float*)d_in[14];
  const float* ln2o = (const float*)d_in[15];

  char* ws = (char*)d_ws;
  const size_t MB = 1ull << 20;
  __hip_bfloat16* WqkvT = (__hip_bfloat16*)(ws + 0 * MB);   // 6 MB (q|k|v rows)
  __hip_bfloat16* WoT   = (__hip_bfloat16*)(ws + 6 * MB);   // 2 MB
  __hip_bfloat16* W1T   = (__hip_bfloat16*)(ws + 8 * MB);   // 8 MB
  __hip_bfloat16* W2T   = (__hip_bfloat16*)(ws + 16 * MB);  // 8 MB
  __hip_bfloat16* hB    = (__hip_bfloat16*)(ws + 24 * MB);  // 8 MB (dead after QKV)
  __hip_bfloat16* qkv   = (__hip_bfloat16*)(ws + 32 * MB);  // 24 MB (dead after attn)
  __hip_bfloat16* aoB   = (__hip_bfloat16*)(ws + 56 * MB);  // 8 MB (dead after Wo)
  float*          oF2   = (float*)(ws + 64 * MB);           // 32 MB, 2 partials (dead after ln1)
  float*          atF   = (float*)(ws + 96 * MB);           // 16 MB
  __hip_bfloat16* atB   = (__hip_bfloat16*)(ws + 24 * MB);  // 8 MB (aliases hB)
  __hip_bfloat16* ff1   = (__hip_bfloat16*)(ws + 32 * MB);  // 32 MB (aliases qkv+aoB)
  float*          ff2   = (float*)(ws + 64 * MB);           // 32 MB, 2 partials (aliases oF2)
  // high-water: 112 MB

  dim3 blk(256);

  k_transpose_bf16<<<dim3(TD / 32, TD / 32), blk, 0, stream>>>(Wq, WqkvT, TD, TD);
  k_transpose_bf16<<<dim3(TD / 32, TD / 32), blk, 0, stream>>>(Wk, WqkvT + (size_t)TD * TD, TD, TD);
  k_transpose_bf16<<<dim3(TD / 32, TD / 32), blk, 0, stream>>>(Wv, WqkvT + (size_t)2 * TD * TD, TD, TD);
  k_transpose_bf16<<<dim3(TD / 32, TD / 32), blk, 0, stream>>>(Wo, WoT, TD, TD);
  k_transpose_bf16<<<dim3(TFF / 32, TD / 32), blk, 0, stream>>>(W1, W1T, TD, TFF);
  k_transpose_bf16<<<dim3(TD / 32, TFF / 32), blk, 0, stream>>>(W2, W2T, TFF, TD);

  k_addpos<<<(TM * TD / 4 + 255) / 256, blk, 0, stream>>>(x, pos, hB, TM * TD / 4);

  // QKV fused: (4096 x 1024) * (3072 x 1024)^T -> bf16 qkv (ldc = 3072)
  k_gemm<0><<<dim3(TM / 128, 3072 / 128, 1), blk, 0, stream>>>(
      hB, WqkvT, qkv, nullptr, TM, 3072, TD, TD, TD);

  k_attn<<<TB * TH * TS / 4, blk, 0, stream>>>(qkv, rpe, aoB);

  // Wo: split-K=2 -> two f32 partials
  k_gemm<2><<<dim3(TM / 128, TD / 128, 2), blk, 0, stream>>>(
      aoB, WoT, oF2, nullptr, TM, TD, TD / 2, TD, TD);

  k_ln1<<<TM, blk, 0, stream>>>(x, pos, oF2, oF2 + (size_t)TM * TD, ln1s, ln1o, atF, atB);

  // FFN1: bias+relu -> bf16
  k_gemm<1><<<dim3(TM / 128, TFF / 128, 1), blk, 0, stream>>>(
      atB, W1T, ff1, b1, TM, TFF, TD, TD, TD);

  // FFN2: split-K=2 -> two f32 partials
  k_gemm<2><<<dim3(TM / 128, TD / 128, 2), blk, 0, stream>>>(
      ff1, W2T, ff2, nullptr, TM, TD, TFF / 2, TFF, TFF);

  k_ln2<<<TM, blk, 0, stream>>>(ff2, ff2 + (size_t)TM * TD, atF, b2, ln2s, ln2o,
                                (float*)d_out);
}

// Round 3
// 227.983 us; speedup vs baseline: 2.0346x; 1.4497x over previous
//
#include <hip/hip_runtime.h>
#include <hip/hip_bf16.h>

#define DEVI static __device__ __forceinline__

typedef __attribute__((ext_vector_type(4))) float f32x4;
typedef __attribute__((ext_vector_type(8))) short bf16x8;
typedef __attribute__((ext_vector_type(4))) short s16x4;

constexpr int TB  = 2;      // batch
constexpr int TS  = 2048;   // seq len
constexpr int TD  = 1024;   // model dim
constexpr int TH  = 16;     // heads
constexpr int TDH = 64;     // head dim
constexpr int TC  = 64;     // window size
constexpr int TFF = 4096;   // ffn dim
constexpr int TM  = TB * TS;  // 4096 rows

DEVI float bf2f(short s) {
  return __builtin_bit_cast(float, (unsigned)((unsigned short)s) << 16);
}
DEVI short f2bf(float f) {
  return __builtin_bit_cast(short, __float2bfloat16(f));
}

// async global->LDS, 16B per lane, dest = wave-uniform base + lane*16
#define GLD16(gp, lp)                                              \
  __builtin_amdgcn_global_load_lds(                                \
      (const __attribute__((address_space(1))) void*)(gp),         \
      (__attribute__((address_space(3))) void*)(lp), 16, 0, 0)

// ---------------- weight transpose + f32->bf16 convert --------------------
// W (K x N) f32 row-major  ->  WT (N x K) bf16 row-major
__global__ __launch_bounds__(256) void k_transpose_bf16(
    const float* __restrict__ W, __hip_bfloat16* __restrict__ WT, int K, int N) {
  __shared__ float tile[32][33];
  int n0 = blockIdx.x * 32, k0 = blockIdx.y * 32;
  int tx = threadIdx.x & 31, ty = threadIdx.x >> 5;  // 32 x 8
  for (int i = 0; i < 32; i += 8)
    tile[ty + i][tx] = W[(size_t)(k0 + ty + i) * N + n0 + tx];
  __syncthreads();
  for (int i = 0; i < 32; i += 8)
    WT[(size_t)(n0 + ty + i) * K + k0 + tx] = __float2bfloat16(tile[tx][ty + i]);
}

// ---------------- h = x + pos[t % C] (bf16 only) --------------------------
__global__ __launch_bounds__(256) void k_addpos(
    const float* __restrict__ x, const float* __restrict__ pos,
    __hip_bfloat16* __restrict__ hb, int total4) {
  int i = blockIdx.x * 256 + threadIdx.x;
  if (i >= total4) return;
  int e = i * 4;
  int d = e & (TD - 1);
  int t = (e / TD) & (TS - 1);
  f32x4 xv = *(const f32x4*)(x + e);
  f32x4 pv = *(const f32x4*)(pos + (size_t)(t & (TC - 1)) * TD + d);
  s16x4 hb4;
  for (int j = 0; j < 4; j++) hb4[j] = f2bf(xv[j] + pv[j]);
  *(s16x4*)((short*)hb + e) = hb4;
}

// ---------------- bf16 MFMA GEMM (m97-style + 2-phase dbuf) ---------------
template <int EPI>
__global__ __launch_bounds__(256) void k_gemm(
    const __hip_bfloat16* __restrict__ A, const __hip_bfloat16* __restrict__ BT,
    void* __restrict__ Cout, const float* __restrict__ bias,
    int M, int N, int K, int lda, int ldb) {
  constexpr int BM = 128, BN = 128, BK = 32;
  __shared__ __align__(16) __hip_bfloat16 As[2][BM * BK];
  __shared__ __align__(16) __hip_bfloat16 Bs[2][BN * BK];
  int tid = threadIdx.x;
  int lane = tid & 63, wave = tid >> 6;
  int wm = wave >> 1, wn = wave & 1;
  int fr = lane & 15, fg = lane >> 4;
  int m0 = blockIdx.x * BM, n0 = blockIdx.y * BN;
  size_t koff = (size_t)blockIdx.z * K;
  const __hip_bfloat16* Ab = A + koff;
  const __hip_bfloat16* Bb = BT + koff;

  auto stage = [&](int s, int k0) {
#pragma unroll
    for (int i = 0; i < 2; i++) {
      int c = (wave * 2 + i) * 64 + lane;
      int row = c >> 2, seg = (c & 3) ^ (row & 3);
      GLD16(Ab + (size_t)(m0 + row) * lda + k0 + seg * 8,
            (char*)&As[s][0] + (wave * 2 + i) * 1024);
      GLD16(Bb + (size_t)(n0 + row) * ldb + k0 + seg * 8,
            (char*)&Bs[s][0] + (wave * 2 + i) * 1024);
    }
  };

  f32x4 acc[4][4] = {};
  const int nt = K / BK;
  stage(0, 0);
  __syncthreads();
  for (int t = 0; t < nt; t++) {
    int cur = t & 1;
    if (t + 1 < nt) stage(cur ^ 1, (t + 1) * BK);
    bf16x8 af[4], bfv[4];
#pragma unroll
    for (int m = 0; m < 4; m++) {
      int row = wm * 64 + m * 16 + fr;
      af[m] = *(const bf16x8*)((const char*)&As[cur][0] + row * 64 +
                               ((fg ^ (row & 3)) * 16));
    }
#pragma unroll
    for (int n = 0; n < 4; n++) {
      int row = wn * 64 + n * 16 + fr;
      bfv[n] = *(const bf16x8*)((const char*)&Bs[cur][0] + row * 64 +
                                ((fg ^ (row & 3)) * 16));
    }
#pragma unroll
    for (int m = 0; m < 4; m++)
#pragma unroll
      for (int n = 0; n < 4; n++)
        acc[m][n] = __builtin_amdgcn_mfma_f32_16x16x32_bf16(af[m], bfv[n],
                                                            acc[m][n], 0, 0, 0);
    __syncthreads();
  }

  float* Cf = (float*)Cout + (size_t)blockIdx.z * M * N;
#pragma unroll
  for (int m = 0; m < 4; m++)
#pragma unroll
    for (int n = 0; n < 4; n++) {
      int col = n0 + wn * 64 + n * 16 + fr;
#pragma unroll
      for (int j = 0; j < 4; j++) {
        int row = m0 + wm * 64 + m * 16 + fg * 4 + j;
        float v = acc[m][n][j];
        if (EPI == 1) { v += bias[col]; v = fmaxf(v, 0.f); }
        if (EPI == 2)
          Cf[(size_t)row * N + col] = v;
        else
          ((__hip_bfloat16*)Cout)[(size_t)row * N + col] = __float2bfloat16(v);
      }
    }
}

// ---------------- V transpose: qkv v-slice -> vT[bh][64 d][2048 t] --------
__global__ __launch_bounds__(256) void k_vtrans(
    const __hip_bfloat16* __restrict__ qkv, __hip_bfloat16* __restrict__ vT) {
  __shared__ short tile[64][68];  // [t][d], pad->136B row stride
  int bh = blockIdx.x;            // b*16+h
  int tb = blockIdx.y;            // 64-row t block
  int b = bh >> 4, h = bh & 15;
  int tid = threadIdx.x;
#pragma unroll
  for (int i = 0; i < 2; i++) {
    int c = i * 256 + tid;        // 512 chunks of 8 elems
    int trow = c >> 3, seg = c & 7;
    bf16x8 v = *(const bf16x8*)((const short*)qkv +
        (size_t)(b * TS + tb * 64 + trow) * 3072 + 2048 + h * TDH + seg * 8);
    s16x4 lo = {v[0], v[1], v[2], v[3]}, hi = {v[4], v[5], v[6], v[7]};
    *(s16x4*)&tile[trow][seg * 8] = lo;       // 8B-aligned (136B rows)
    *(s16x4*)&tile[trow][seg * 8 + 4] = hi;
  }
  __syncthreads();
#pragma unroll
  for (int i2 = 0; i2 < 2; i2++) {
    int c = i2 * 256 + tid;
    int d = c >> 3, ts = c & 7;   // output row d, t-chunk ts
    bf16x8 o;
#pragma unroll
    for (int j = 0; j < 8; j++) o[j] = tile[ts * 8 + j][d];
    *(bf16x8*)((short*)vT + (size_t)bh * TDH * TS + (size_t)d * TS +
               tb * 64 + ts * 8) = o;
  }
}

// ---------------- sliding-window attention (MFMA) --------------------------
// block = (b, h, 64-query tile); 4 waves, each owns 16 query rows.
// K block: keys t0-64 .. t0+63 (128 rows) staged via GLD16 + slot^(row&7).
// VT block: vT[d][t0-64 .. t0+63] staged via GLD16 + slot^(row&15).
// S = Q*K^T (16x128 per wave), mask (0<=d<64 && T>=0), softmax over 16-lane
// groups, P -> LDS [16][136] bf16, O = P*VT^T via MFMA.
__global__ __launch_bounds__(256) void k_attn(
    const __hip_bfloat16* __restrict__ qkv, const __hip_bfloat16* __restrict__ vT,
    const float* __restrict__ rpe, __hip_bfloat16* __restrict__ out) {
  __shared__ __align__(16) short K_lds[128 * 64];    // [jj][64k], 128B rows, swz
  __shared__ __align__(16) short VT_lds[64 * 128];   // [d][128jj], 256B rows, swz
  __shared__ __align__(16) short P_lds[4][16 * 136]; // per-wave [q][jj], pad
  __shared__ float rpe_lds[TC];
  int tid = threadIdx.x, lane = tid & 63, wave = tid >> 6;
  int fr = lane & 15, g = lane >> 4;
  int blk = blockIdx.x;           // (b*16+h)*32 + qt
  int qt = blk & 31, bh = blk >> 5;
  int h = bh & 15, b = bh >> 4;
  int t0 = qt * 64;
  const short* qg = (const short*)qkv;

  if (tid < TC) rpe_lds[tid] = rpe[h * TC + tid];

  // stage K: 1024 x 16B chunks; row=c>>3 (jj), slot=c&7, seg=slot^(row&7)
#pragma unroll
  for (int i = 0; i < 4; i++) {
    int cb = i * 256 + wave * 64;
    int c = cb + lane;
    int row = c >> 3, slot = c & 7;
    int seg = slot ^ (row & 7);
    int kr = t0 - 64 + row; if (kr < 0) kr = 0;
    GLD16(qg + ((size_t)(b * TS + kr) * 3072 + 1024 + h * TDH + seg * 8),
          (char*)K_lds + cb * 16);
  }
  // stage VT: 1024 x 16B chunks; row=c>>4 (d), slot=c&15, seg=slot^(row&15)
  const short* vg = (const short*)vT + (size_t)bh * TDH * TS;
#pragma unroll
  for (int i = 0; i < 4; i++) {
    int cb = i * 256 + wave * 64;
    int c = cb + lane;
    int row = c >> 4, slot = c & 15;
    int seg = slot ^ (row & 15);
    int tc = t0 - 64 + seg * 8; if (tc < 0) tc = 0;
    GLD16(vg + (size_t)row * TS + tc, (char*)VT_lds + cb * 16);
  }

  // Q fragments straight from global (rows t0 + wave*16 + fr)
  int qrow = t0 + wave * 16 + fr;
  const short* qptr = qg + ((size_t)(b * TS + qrow) * 3072 + h * TDH + g * 8);
  bf16x8 qf0 = *(const bf16x8*)qptr;
  bf16x8 qf1 = *(const bf16x8*)(qptr + 32);

  __syncthreads();  // drains GLD16 (vmcnt) + barrier

  // QK^T: S[q=g*4+r][jj=nt*16+fr], 8 ntiles x 2 ksteps
  f32x4 S[8] = {};
#pragma unroll
  for (int kk = 0; kk < 2; kk++) {
    bf16x8 a = kk ? qf1 : qf0;
#pragma unroll
    for (int nt = 0; nt < 8; nt++) {
      int row = nt * 16 + fr;
      int slot = (kk * 4 + g) ^ (row & 7);
      bf16x8 bfrag = *(const bf16x8*)((const char*)K_lds + row * 128 + slot * 16);
      S[nt] = __builtin_amdgcn_mfma_f32_16x16x32_bf16(a, bfrag, S[nt], 0, 0, 0);
    }
  }

  // masked softmax per query row; write P (bf16) to this wave's LDS slab
  int wq = wave * 16;
#pragma unroll
  for (int r = 0; r < 4; r++) {
    int ql = g * 4 + r;
    float sc[8];
    float m = -3.4028235e38f;
#pragma unroll
    for (int nt = 0; nt < 8; nt++) {
      int jj = nt * 16 + fr;
      int d = wq + ql + 64 - jj;
      bool valid = (d >= 0) && (d < TC) && (t0 - 64 + jj >= 0);
      float v = valid ? (S[nt][r] * 0.125f + rpe_lds[d & (TC - 1)])
                      : -3.4028235e38f;
      sc[nt] = v;
      m = fmaxf(m, v);
    }
#pragma unroll
    for (int o = 1; o < 16; o <<= 1) m = fmaxf(m, __shfl_xor(m, o));
    float p[8], sum = 0.f;
#pragma unroll
    for (int nt = 0; nt < 8; nt++) { p[nt] = __expf(sc[nt] - m); sum += p[nt]; }
#pragma unroll
    for (int o = 1; o < 16; o <<= 1) sum += __shfl_xor(sum, o);
    float rs = 1.0f / sum;
#pragma unroll
    for (int nt = 0; nt < 8; nt++)
      P_lds[wave][ql * 136 + nt * 16 + fr] = f2bf(p[nt] * rs);
  }

  // PV: O[q][d] = sum_jj P[q][jj] * VT[d][jj]
  f32x4 O[4] = {};
#pragma unroll
  for (int kk = 0; kk < 4; kk++) {
    bf16x8 pa = *(const bf16x8*)((const char*)&P_lds[wave][0] +
                                 fr * 272 + kk * 64 + g * 16);
#pragma unroll
    for (int dt = 0; dt < 4; dt++) {
      int row = dt * 16 + fr;
      int slot = (kk * 4 + g) ^ (row & 15);
      bf16x8 vb = *(const bf16x8*)((const char*)VT_lds + row * 256 + slot * 16);
      O[dt] = __builtin_amdgcn_mfma_f32_16x16x32_bf16(pa, vb, O[dt], 0, 0, 0);
    }
  }

  // store: O[q=g*4+r][d=dt*16+fr]
  size_t ob = ((size_t)(b * TS + t0 + wq + g * 4)) * TD + h * TDH;
#pragma unroll
  for (int dt = 0; dt < 4; dt++)
#pragma unroll
    for (int r = 0; r < 4; r++)
      ((short*)out)[ob + (size_t)r * TD + dt * 16 + fr] = f2bf(O[dt][r]);
}

// ---------------- LayerNorm (two-pass, fused residual + split-K sum) ------
DEVI float block_sum(float v, float* red) {
  for (int o = 32; o; o >>= 1) v += __shfl_xor(v, o);
  int wave = threadIdx.x >> 6;
  if ((threadIdx.x & 63) == 0) red[wave] = v;
  __syncthreads();
  float r = red[0] + red[1] + red[2] + red[3];
  __syncthreads();
  return r;
}

__global__ __launch_bounds__(256) void k_ln1(
    const float* __restrict__ x, const float* __restrict__ pos,
    const float* __restrict__ P0, const float* __restrict__ P1,
    const float* __restrict__ scale, const float* __restrict__ offset,
    float* __restrict__ outf, __hip_bfloat16* __restrict__ outb) {
  __shared__ float red[4];
  int row = blockIdx.x, tid = threadIdx.x;
  int t = row & (TS - 1), pr = t & (TC - 1);
  size_t base = (size_t)row * TD + tid * 4;
  f32x4 xv = *(const f32x4*)(x + base);
  f32x4 pv = *(const f32x4*)(pos + (size_t)pr * TD + tid * 4);
  f32x4 a0 = *(const f32x4*)(P0 + base);
  f32x4 a1 = *(const f32x4*)(P1 + base);
  xv = xv + pv + a0 + a1;
  float s = xv[0] + xv[1] + xv[2] + xv[3];
  s = block_sum(s, red);
  float mu = s * (1.f / TD);
  float s2 = 0.f;
  for (int j = 0; j < 4; j++) { float dlt = xv[j] - mu; s2 += dlt * dlt; }
  s2 = block_sum(s2, red);
  float rs = rsqrtf(s2 * (1.f / TD) + 1e-5f);
  f32x4 sc = *(const f32x4*)(scale + tid * 4);
  f32x4 of = *(const f32x4*)(offset + tid * 4);
  f32x4 y;
  for (int j = 0; j < 4; j++) y[j] = (xv[j] - mu) * rs * sc[j] + of[j];
  *(f32x4*)(outf + base) = y;
  s16x4 pb;
  for (int j = 0; j < 4; j++) pb[j] = f2bf(y[j]);
  *(s16x4*)((short*)outb + base) = pb;
}

__global__ __launch_bounds__(256) void k_ln2(
    const float* __restrict__ P0, const float* __restrict__ P1,
    const float* __restrict__ R, const float* __restrict__ bias,
    const float* __restrict__ scale, const float* __restrict__ offset,
    float* __restrict__ outf) {
  __shared__ float red[4];
  int row = blockIdx.x, tid = threadIdx.x;
  size_t base = (size_t)row * TD + tid * 4;
  f32x4 a0 = *(const f32x4*)(P0 + base);
  f32x4 a1 = *(const f32x4*)(P1 + base);
  f32x4 rv = *(const f32x4*)(R + base);
  f32x4 bi = *(const f32x4*)(bias + tid * 4);
  f32x4 xv = a0 + a1 + rv + bi;
  float s = xv[0] + xv[1] + xv[2] + xv[3];
  s = block_sum(s, red);
  float mu = s * (1.f / TD);
  float s2 = 0.f;
  for (int j = 0; j < 4; j++) { float dlt = xv[j] - mu; s2 += dlt * dlt; }
  s2 = block_sum(s2, red);
  float rs = rsqrtf(s2 * (1.f / TD) + 1e-5f);
  f32x4 sc = *(const f32x4*)(scale + tid * 4);
  f32x4 of = *(const f32x4*)(offset + tid * 4);
  f32x4 y;
  for (int j = 0; j < 4; j++) y[j] = (xv[j] - mu) * rs * sc[j] + of[j];
  *(f32x4*)(outf + base) = y;
}

// --------------------------------------------------------------------------
extern "C" void kernel_launch(void* const* d_in, const int* in_sizes, int n_in,
                              void* d_out, int out_size, void* d_ws, size_t ws_size,
                              hipStream_t stream) {
  const float* x    = (const float*)d_in[0];
  const float* pos  = (const float*)d_in[2];
  const float* rpe  = (const float*)d_in[3];
  const float* Wq   = (const float*)d_in[4];
  const float* Wk   = (const float*)d_in[5];
  const float* Wv   = (const float*)d_in[6];
  const float* Wo   = (const float*)d_in[7];
  const float* ln1s = (const float*)d_in[8];
  const float* ln1o = (const float*)d_in[9];
  const float* W1   = (const float*)d_in[10];
  const float* b1   = (const float*)d_in[11];
  const float* W2   = (const float*)d_in[12];
  const float* b2   = (const float*)d_in[13];
  const float* ln2s = (const float*)d_in[14];
  const float* ln2o = (const float*)d_in[15];

  char* ws = (char*)d_ws;
  const size_t MB = 1ull << 20;
  __hip_bfloat16* WqkvT = (__hip_bfloat16*)(ws + 0 * MB);   // 6 MB
  __hip_bfloat16* WoT   = (__hip_bfloat16*)(ws + 6 * MB);   // 2 MB
  __hip_bfloat16* W1T   = (__hip_bfloat16*)(ws + 8 * MB);   // 8 MB
  __hip_bfloat16* W2T   = (__hip_bfloat16*)(ws + 16 * MB);  // 8 MB
  __hip_bfloat16* hB    = (__hip_bfloat16*)(ws + 24 * MB);  // 8 MB (dead after QKV)
  __hip_bfloat16* qkv   = (__hip_bfloat16*)(ws + 32 * MB);  // 24 MB (dead after attn)
  __hip_bfloat16* aoB   = (__hip_bfloat16*)(ws + 56 * MB);  // 8 MB (dead after Wo)
  float*          oF2   = (float*)(ws + 64 * MB);           // 32 MB (dead after ln1)
  float*          atF   = (float*)(ws + 96 * MB);           // 16 MB
  __hip_bfloat16* atB   = (__hip_bfloat16*)(ws + 24 * MB);  // 8 MB (aliases hB)
  __hip_bfloat16* ff1   = (__hip_bfloat16*)(ws + 32 * MB);  // 32 MB (aliases qkv+aoB)
  float*          ff2   = (float*)(ws + 64 * MB);           // 32 MB (aliases oF2)
  __hip_bfloat16* vTb   = (__hip_bfloat16*)(ws + 112 * MB); // 8 MB (dead after attn)
  // high-water: 120 MB

  dim3 blk(256);

  k_transpose_bf16<<<dim3(TD / 32, TD / 32), blk, 0, stream>>>(Wq, WqkvT, TD, TD);
  k_transpose_bf16<<<dim3(TD / 32, TD / 32), blk, 0, stream>>>(Wk, WqkvT + (size_t)TD * TD, TD, TD);
  k_transpose_bf16<<<dim3(TD / 32, TD / 32), blk, 0, stream>>>(Wv, WqkvT + (size_t)2 * TD * TD, TD, TD);
  k_transpose_bf16<<<dim3(TD / 32, TD / 32), blk, 0, stream>>>(Wo, WoT, TD, TD);
  k_transpose_bf16<<<dim3(TFF / 32, TD / 32), blk, 0, stream>>>(W1, W1T, TD, TFF);
  k_transpose_bf16<<<dim3(TD / 32, TFF / 32), blk, 0, stream>>>(W2, W2T, TFF, TD);

  k_addpos<<<(TM * TD / 4 + 255) / 256, blk, 0, stream>>>(x, pos, hB, TM * TD / 4);

  // QKV fused: (4096 x 1024) * (3072 x 1024)^T -> bf16 qkv
  k_gemm<0><<<dim3(TM / 128, 3072 / 128, 1), blk, 0, stream>>>(
      hB, WqkvT, qkv, nullptr, TM, 3072, TD, TD, TD);

  k_vtrans<<<dim3(TB * TH, TS / 64), blk, 0, stream>>>(qkv, vTb);
  k_attn<<<TB * TH * (TS / 64), blk, 0, stream>>>(qkv, vTb, rpe, aoB);

  // Wo: split-K=2 -> two f32 partials
  k_gemm<2><<<dim3(TM / 128, TD / 128, 2), blk, 0, stream>>>(
      aoB, WoT, oF2, nullptr, TM, TD, TD / 2, TD, TD);

  k_ln1<<<TM, blk, 0, stream>>>(x, pos, oF2, oF2 + (size_t)TM * TD, ln1s, ln1o, atF, atB);

  // FFN1: bias+relu -> bf16
  k_gemm<1><<<dim3(TM / 128, TFF / 128, 1), blk, 0, stream>>>(
      atB, W1T, ff1, b1, TM, TFF, TD, TD, TD);

  // FFN2: split-K=2 -> two f32 partials
  k_gemm<2><<<dim3(TM / 128, TD / 128, 2), blk, 0, stream>>>(
      ff1, W2T, ff2, nullptr, TM, TD, TFF / 2, TFF, TFF);

  k_ln2<<<TM, blk, 0, stream>>>(ff2, ff2 + (size_t)TM * TD, atF, b2, ln2s, ln2o,
                                (float*)d_out);
}

// Round 4
// 217.012 us; speedup vs baseline: 2.1374x; 1.0506x over previous
//
#include <hip/hip_runtime.h>
#include <hip/hip_bf16.h>

#define DEVI static __device__ __forceinline__

typedef __attribute__((ext_vector_type(4))) float f32x4;
typedef __attribute__((ext_vector_type(8))) short bf16x8;
typedef __attribute__((ext_vector_type(4))) short s16x4;

constexpr int TB  = 2;      // batch
constexpr int TS  = 2048;   // seq len
constexpr int TD  = 1024;   // model dim
constexpr int TH  = 16;     // heads
constexpr int TDH = 64;     // head dim
constexpr int TC  = 64;     // window size
constexpr int TFF = 4096;   // ffn dim
constexpr int TM  = TB * TS;  // 4096 rows

DEVI float bf2f(short s) {
  return __builtin_bit_cast(float, (unsigned)((unsigned short)s) << 16);
}
DEVI short f2bf(float f) {
  return __builtin_bit_cast(short, __float2bfloat16(f));
}

// async global->LDS, 16B per lane, dest = wave-uniform base + lane*16
#define GLD16(gp, lp)                                              \
  __builtin_amdgcn_global_load_lds(                                \
      (const __attribute__((address_space(1))) void*)(gp),         \
      (__attribute__((address_space(3))) void*)(lp), 16, 0, 0)

// counted vmcnt wait (N = max loads allowed outstanding), compiler-fenced
#define WAITVM(N) asm volatile("s_waitcnt vmcnt(" #N ")" ::: "memory")

// ---------------- weight transpose + f32->bf16 convert --------------------
// W (K x N) f32 row-major  ->  WT (N x K) bf16 row-major
__global__ __launch_bounds__(256) void k_transpose_bf16(
    const float* __restrict__ W, __hip_bfloat16* __restrict__ WT, int K, int N) {
  __shared__ float tile[32][33];
  int n0 = blockIdx.x * 32, k0 = blockIdx.y * 32;
  int tx = threadIdx.x & 31, ty = threadIdx.x >> 5;  // 32 x 8
  for (int i = 0; i < 32; i += 8)
    tile[ty + i][tx] = W[(size_t)(k0 + ty + i) * N + n0 + tx];
  __syncthreads();
  for (int i = 0; i < 32; i += 8)
    WT[(size_t)(n0 + ty + i) * K + k0 + tx] = __float2bfloat16(tile[tx][ty + i]);
}

// ---------------- h = x + pos[t % C] (bf16 only) --------------------------
__global__ __launch_bounds__(256) void k_addpos(
    const float* __restrict__ x, const float* __restrict__ pos,
    __hip_bfloat16* __restrict__ hb, int total4) {
  int i = blockIdx.x * 256 + threadIdx.x;
  if (i >= total4) return;
  int e = i * 4;
  int d = e & (TD - 1);
  int t = (e / TD) & (TS - 1);
  f32x4 xv = *(const f32x4*)(x + e);
  f32x4 pv = *(const f32x4*)(pos + (size_t)(t & (TC - 1)) * TD + d);
  s16x4 hb4;
  for (int j = 0; j < 4; j++) hb4[j] = f2bf(xv[j] + pv[j]);
  *(s16x4*)((short*)hb + e) = hb4;
}

// ---------------- bf16 MFMA GEMM: 3-stage pipeline, counted vmcnt ---------
// C = A(MxK) * BT(NxK)^T.  BM=BN=128, BK=32, 4 waves (2x2), triple-buffered
// K-tiles.  Iter t: vmcnt(4) [tile t landed, t+1 in flight] -> barrier ->
// ds_read buf[t%3] -> stage tile t+2 into buf[(t+2)%3] -> MFMA.
// Swizzle: LDS slot s of row r holds global k-octet s^((r>>1)&3) (2-way max).
// EPI: 0 = store bf16, 1 = bias+relu -> bf16, 2 = store f32 (split-K partials)
template <int EPI>
__global__ __launch_bounds__(256, 3) void k_gemm(
    const __hip_bfloat16* __restrict__ A, const __hip_bfloat16* __restrict__ BT,
    void* __restrict__ Cout, const float* __restrict__ bias,
    int M, int N, int K, int lda, int ldb) {
  constexpr int BM = 128, BN = 128, BK = 32;
  __shared__ __align__(16) __hip_bfloat16 As[3][BM * BK];  // 3 x 8 KB
  __shared__ __align__(16) __hip_bfloat16 Bs[3][BN * BK];  // 3 x 8 KB
  int tid = threadIdx.x;
  int lane = tid & 63, wave = tid >> 6;
  int wm = wave >> 1, wn = wave & 1;
  int fr = lane & 15, fg = lane >> 4;
  int m0 = blockIdx.x * BM, n0 = blockIdx.y * BN;
  size_t koff = (size_t)blockIdx.z * K;
  const __hip_bfloat16* Ab = A + koff;
  const __hip_bfloat16* Bb = BT + koff;

  // stage tile k0 into buffer s: chunk c=(row,slot) holds global seg=slot^((row>>1)&3)
  auto stage = [&](int s, int k0) {
#pragma unroll
    for (int i = 0; i < 2; i++) {
      int c = (wave * 2 + i) * 64 + lane;
      int row = c >> 2, seg = (c & 3) ^ ((row >> 1) & 3);
      GLD16(Ab + (size_t)(m0 + row) * lda + k0 + seg * 8,
            (char*)&As[s][0] + (wave * 2 + i) * 1024);
      GLD16(Bb + (size_t)(n0 + row) * ldb + k0 + seg * 8,
            (char*)&Bs[s][0] + (wave * 2 + i) * 1024);
    }
  };

  f32x4 acc[4][4] = {};
  const int nt = K / BK;
  stage(0, 0);
  stage(1, BK);
  int cur = 0;
  for (int t = 0; t < nt; t++) {
    if (t + 1 < nt) { WAITVM(4); } else { WAITVM(0); }
    __builtin_amdgcn_s_barrier();
    asm volatile("" ::: "memory");
    bf16x8 af[4], bfv[4];
#pragma unroll
    for (int m = 0; m < 4; m++) {
      int row = wm * 64 + m * 16 + fr;
      af[m] = *(const bf16x8*)((const char*)&As[cur][0] + row * 64 +
                               ((fg ^ ((row >> 1) & 3)) * 16));
    }
#pragma unroll
    for (int n = 0; n < 4; n++) {
      int row = wn * 64 + n * 16 + fr;
      bfv[n] = *(const bf16x8*)((const char*)&Bs[cur][0] + row * 64 +
                                ((fg ^ ((row >> 1) & 3)) * 16));
    }
    if (t + 2 < nt) {
      int nb = cur + 2; if (nb >= 3) nb -= 3;
      stage(nb, (t + 2) * BK);
    }
    __builtin_amdgcn_s_setprio(1);
#pragma unroll
    for (int m = 0; m < 4; m++)
#pragma unroll
      for (int n = 0; n < 4; n++)
        acc[m][n] = __builtin_amdgcn_mfma_f32_16x16x32_bf16(af[m], bfv[n],
                                                            acc[m][n], 0, 0, 0);
    __builtin_amdgcn_s_setprio(0);
    cur++; if (cur == 3) cur = 0;
  }

  float* Cf = (float*)Cout + (size_t)blockIdx.z * M * N;
#pragma unroll
  for (int m = 0; m < 4; m++)
#pragma unroll
    for (int n = 0; n < 4; n++) {
      int col = n0 + wn * 64 + n * 16 + fr;
#pragma unroll
      for (int j = 0; j < 4; j++) {
        int row = m0 + wm * 64 + m * 16 + fg * 4 + j;
        float v = acc[m][n][j];
        if (EPI == 1) { v += bias[col]; v = fmaxf(v, 0.f); }
        if (EPI == 2)
          Cf[(size_t)row * N + col] = v;
        else
          ((__hip_bfloat16*)Cout)[(size_t)row * N + col] = __float2bfloat16(v);
      }
    }
}

// ---------------- V transpose: qkv v-slice -> vT[bh][64 d][2048 t] --------
__global__ __launch_bounds__(256) void k_vtrans(
    const __hip_bfloat16* __restrict__ qkv, __hip_bfloat16* __restrict__ vT) {
  __shared__ short tile[64][68];  // [t][d], pad->136B row stride
  int bh = blockIdx.x;            // b*16+h
  int tb = blockIdx.y;            // 64-row t block
  int b = bh >> 4, h = bh & 15;
  int tid = threadIdx.x;
#pragma unroll
  for (int i = 0; i < 2; i++) {
    int c = i * 256 + tid;        // 512 chunks of 8 elems
    int trow = c >> 3, seg = c & 7;
    bf16x8 v = *(const bf16x8*)((const short*)qkv +
        (size_t)(b * TS + tb * 64 + trow) * 3072 + 2048 + h * TDH + seg * 8);
    s16x4 lo = {v[0], v[1], v[2], v[3]}, hi = {v[4], v[5], v[6], v[7]};
    *(s16x4*)&tile[trow][seg * 8] = lo;
    *(s16x4*)&tile[trow][seg * 8 + 4] = hi;
  }
  __syncthreads();
#pragma unroll
  for (int i2 = 0; i2 < 2; i2++) {
    int c = i2 * 256 + tid;
    int d = c >> 3, ts = c & 7;   // output row d, t-chunk ts
    bf16x8 o;
#pragma unroll
    for (int j = 0; j < 8; j++) o[j] = tile[ts * 8 + j][d];
    *(bf16x8*)((short*)vT + (size_t)bh * TDH * TS + (size_t)d * TS +
               tb * 64 + ts * 8) = o;
  }
}

// ---------------- sliding-window attention (MFMA) --------------------------
__global__ __launch_bounds__(256) void k_attn(
    const __hip_bfloat16* __restrict__ qkv, const __hip_bfloat16* __restrict__ vT,
    const float* __restrict__ rpe, __hip_bfloat16* __restrict__ out) {
  __shared__ __align__(16) short K_lds[128 * 64];    // [jj][64k], 128B rows, swz
  __shared__ __align__(16) short VT_lds[64 * 128];   // [d][128jj], 256B rows, swz
  __shared__ __align__(16) short P_lds[4][16 * 136]; // per-wave [q][jj], pad
  __shared__ float rpe_lds[TC];
  int tid = threadIdx.x, lane = tid & 63, wave = tid >> 6;
  int fr = lane & 15, g = lane >> 4;
  int blk = blockIdx.x;           // (b*16+h)*32 + qt
  int qt = blk & 31, bh = blk >> 5;
  int h = bh & 15, b = bh >> 4;
  int t0 = qt * 64;
  const short* qg = (const short*)qkv;

  if (tid < TC) rpe_lds[tid] = rpe[h * TC + tid];

  // stage K: 1024 x 16B chunks; row=c>>3 (jj), slot=c&7, seg=slot^(row&7)
#pragma unroll
  for (int i = 0; i < 4; i++) {
    int cb = i * 256 + wave * 64;
    int c = cb + lane;
    int row = c >> 3, slot = c & 7;
    int seg = slot ^ (row & 7);
    int kr = t0 - 64 + row; if (kr < 0) kr = 0;
    GLD16(qg + ((size_t)(b * TS + kr) * 3072 + 1024 + h * TDH + seg * 8),
          (char*)K_lds + cb * 16);
  }
  // stage VT: 1024 x 16B chunks; row=c>>4 (d), slot=c&15, seg=slot^(row&15)
  const short* vg = (const short*)vT + (size_t)bh * TDH * TS;
#pragma unroll
  for (int i = 0; i < 4; i++) {
    int cb = i * 256 + wave * 64;
    int c = cb + lane;
    int row = c >> 4, slot = c & 15;
    int seg = slot ^ (row & 15);
    int tc = t0 - 64 + seg * 8; if (tc < 0) tc = 0;
    GLD16(vg + (size_t)row * TS + tc, (char*)VT_lds + cb * 16);
  }

  // Q fragments straight from global (rows t0 + wave*16 + fr)
  int qrow = t0 + wave * 16 + fr;
  const short* qptr = qg + ((size_t)(b * TS + qrow) * 3072 + h * TDH + g * 8);
  bf16x8 qf0 = *(const bf16x8*)qptr;
  bf16x8 qf1 = *(const bf16x8*)(qptr + 32);

  __syncthreads();  // drains GLD16 (vmcnt) + barrier

  // QK^T: S[q=g*4+r][jj=nt*16+fr], 8 ntiles x 2 ksteps
  f32x4 S[8] = {};
#pragma unroll
  for (int kk = 0; kk < 2; kk++) {
    bf16x8 a = kk ? qf1 : qf0;
#pragma unroll
    for (int nt = 0; nt < 8; nt++) {
      int row = nt * 16 + fr;
      int slot = (kk * 4 + g) ^ (row & 7);
      bf16x8 bfrag = *(const bf16x8*)((const char*)K_lds + row * 128 + slot * 16);
      S[nt] = __builtin_amdgcn_mfma_f32_16x16x32_bf16(a, bfrag, S[nt], 0, 0, 0);
    }
  }

  // masked softmax per query row; write P (bf16) to this wave's LDS slab
  int wq = wave * 16;
#pragma unroll
  for (int r = 0; r < 4; r++) {
    int ql = g * 4 + r;
    float sc[8];
    float m = -3.4028235e38f;
#pragma unroll
    for (int nt = 0; nt < 8; nt++) {
      int jj = nt * 16 + fr;
      int d = wq + ql + 64 - jj;
      bool valid = (d >= 0) && (d < TC) && (t0 - 64 + jj >= 0);
      float v = valid ? (S[nt][r] * 0.125f + rpe_lds[d & (TC - 1)])
                      : -3.4028235e38f;
      sc[nt] = v;
      m = fmaxf(m, v);
    }
#pragma unroll
    for (int o = 1; o < 16; o <<= 1) m = fmaxf(m, __shfl_xor(m, o));
    float p[8], sum = 0.f;
#pragma unroll
    for (int nt = 0; nt < 8; nt++) { p[nt] = __expf(sc[nt] - m); sum += p[nt]; }
#pragma unroll
    for (int o = 1; o < 16; o <<= 1) sum += __shfl_xor(sum, o);
    float rs = 1.0f / sum;
#pragma unroll
    for (int nt = 0; nt < 8; nt++)
      P_lds[wave][ql * 136 + nt * 16 + fr] = f2bf(p[nt] * rs);
  }

  // PV: O[q][d] = sum_jj P[q][jj] * VT[d][jj]
  f32x4 O[4] = {};
#pragma unroll
  for (int kk = 0; kk < 4; kk++) {
    bf16x8 pa = *(const bf16x8*)((const char*)&P_lds[wave][0] +
                                 fr * 272 + kk * 64 + g * 16);
#pragma unroll
    for (int dt = 0; dt < 4; dt++) {
      int row = dt * 16 + fr;
      int slot = (kk * 4 + g) ^ (row & 15);
      bf16x8 vb = *(const bf16x8*)((const char*)VT_lds + row * 256 + slot * 16);
      O[dt] = __builtin_amdgcn_mfma_f32_16x16x32_bf16(pa, vb, O[dt], 0, 0, 0);
    }
  }

  // store: O[q=g*4+r][d=dt*16+fr]
  size_t ob = ((size_t)(b * TS + t0 + wq + g * 4)) * TD + h * TDH;
#pragma unroll
  for (int dt = 0; dt < 4; dt++)
#pragma unroll
    for (int r = 0; r < 4; r++)
      ((short*)out)[ob + (size_t)r * TD + dt * 16 + fr] = f2bf(O[dt][r]);
}

// ---------------- LayerNorm (two-pass, fused residual + split-K sum) ------
DEVI float block_sum(float v, float* red) {
  for (int o = 32; o; o >>= 1) v += __shfl_xor(v, o);
  int wave = threadIdx.x >> 6;
  if ((threadIdx.x & 63) == 0) red[wave] = v;
  __syncthreads();
  float r = red[0] + red[1] + red[2] + red[3];
  __syncthreads();
  return r;
}

__global__ __launch_bounds__(256) void k_ln1(
    const float* __restrict__ x, const float* __restrict__ pos,
    const float* __restrict__ P0, const float* __restrict__ P1,
    const float* __restrict__ scale, const float* __restrict__ offset,
    float* __restrict__ outf, __hip_bfloat16* __restrict__ outb) {
  __shared__ float red[4];
  int row = blockIdx.x, tid = threadIdx.x;
  int t = row & (TS - 1), pr = t & (TC - 1);
  size_t base = (size_t)row * TD + tid * 4;
  f32x4 xv = *(const f32x4*)(x + base);
  f32x4 pv = *(const f32x4*)(pos + (size_t)pr * TD + tid * 4);
  f32x4 a0 = *(const f32x4*)(P0 + base);
  f32x4 a1 = *(const f32x4*)(P1 + base);
  xv = xv + pv + a0 + a1;
  float s = xv[0] + xv[1] + xv[2] + xv[3];
  s = block_sum(s, red);
  float mu = s * (1.f / TD);
  float s2 = 0.f;
  for (int j = 0; j < 4; j++) { float dlt = xv[j] - mu; s2 += dlt * dlt; }
  s2 = block_sum(s2, red);
  float rs = rsqrtf(s2 * (1.f / TD) + 1e-5f);
  f32x4 sc = *(const f32x4*)(scale + tid * 4);
  f32x4 of = *(const f32x4*)(offset + tid * 4);
  f32x4 y;
  for (int j = 0; j < 4; j++) y[j] = (xv[j] - mu) * rs * sc[j] + of[j];
  *(f32x4*)(outf + base) = y;
  s16x4 pb;
  for (int j = 0; j < 4; j++) pb[j] = f2bf(y[j]);
  *(s16x4*)((short*)outb + base) = pb;
}

__global__ __launch_bounds__(256) void k_ln2(
    const float* __restrict__ P0, const float* __restrict__ P1,
    const float* __restrict__ R, const float* __restrict__ bias,
    const float* __restrict__ scale, const float* __restrict__ offset,
    float* __restrict__ outf) {
  __shared__ float red[4];
  int row = blockIdx.x, tid = threadIdx.x;
  size_t base = (size_t)row * TD + tid * 4;
  f32x4 a0 = *(const f32x4*)(P0 + base);
  f32x4 a1 = *(const f32x4*)(P1 + base);
  f32x4 rv = *(const f32x4*)(R + base);
  f32x4 bi = *(const f32x4*)(bias + tid * 4);
  f32x4 xv = a0 + a1 + rv + bi;
  float s = xv[0] + xv[1] + xv[2] + xv[3];
  s = block_sum(s, red);
  float mu = s * (1.f / TD);
  float s2 = 0.f;
  for (int j = 0; j < 4; j++) { float dlt = xv[j] - mu; s2 += dlt * dlt; }
  s2 = block_sum(s2, red);
  float rs = rsqrtf(s2 * (1.f / TD) + 1e-5f);
  f32x4 sc = *(const f32x4*)(scale + tid * 4);
  f32x4 of = *(const f32x4*)(offset + tid * 4);
  f32x4 y;
  for (int j = 0; j < 4; j++) y[j] = (xv[j] - mu) * rs * sc[j] + of[j];
  *(f32x4*)(outf + base) = y;
}

// --------------------------------------------------------------------------
extern "C" void kernel_launch(void* const* d_in, const int* in_sizes, int n_in,
                              void* d_out, int out_size, void* d_ws, size_t ws_size,
                              hipStream_t stream) {
  const float* x    = (const float*)d_in[0];
  const float* pos  = (const float*)d_in[2];
  const float* rpe  = (const float*)d_in[3];
  const float* Wq   = (const float*)d_in[4];
  const float* Wk   = (const float*)d_in[5];
  const float* Wv   = (const float*)d_in[6];
  const float* Wo   = (const float*)d_in[7];
  const float* ln1s = (const float*)d_in[8];
  const float* ln1o = (const float*)d_in[9];
  const float* W1   = (const float*)d_in[10];
  const float* b1   = (const float*)d_in[11];
  const float* W2   = (const float*)d_in[12];
  const float* b2   = (const float*)d_in[13];
  const float* ln2s = (const float*)d_in[14];
  const float* ln2o = (const float*)d_in[15];

  char* ws = (char*)d_ws;
  const size_t MB = 1ull << 20;
  __hip_bfloat16* WqkvT = (__hip_bfloat16*)(ws + 0 * MB);   // 6 MB
  __hip_bfloat16* WoT   = (__hip_bfloat16*)(ws + 6 * MB);   // 2 MB
  __hip_bfloat16* W1T   = (__hip_bfloat16*)(ws + 8 * MB);   // 8 MB
  __hip_bfloat16* W2T   = (__hip_bfloat16*)(ws + 16 * MB);  // 8 MB
  __hip_bfloat16* hB    = (__hip_bfloat16*)(ws + 24 * MB);  // 8 MB (dead after QKV)
  __hip_bfloat16* qkv   = (__hip_bfloat16*)(ws + 32 * MB);  // 24 MB (dead after attn)
  __hip_bfloat16* aoB   = (__hip_bfloat16*)(ws + 56 * MB);  // 8 MB (dead after Wo)
  float*          oF2   = (float*)(ws + 64 * MB);           // 32 MB (dead after ln1)
  float*          atF   = (float*)(ws + 96 * MB);           // 16 MB
  __hip_bfloat16* atB   = (__hip_bfloat16*)(ws + 24 * MB);  // 8 MB (aliases hB)
  __hip_bfloat16* ff1   = (__hip_bfloat16*)(ws + 32 * MB);  // 32 MB (aliases qkv+aoB)
  float*          ff2   = (float*)(ws + 64 * MB);           // 32 MB (aliases oF2)
  __hip_bfloat16* vTb   = (__hip_bfloat16*)(ws + 112 * MB); // 8 MB (dead after attn)
  // high-water: 120 MB

  dim3 blk(256);

  k_transpose_bf16<<<dim3(TD / 32, TD / 32), blk, 0, stream>>>(Wq, WqkvT, TD, TD);
  k_transpose_bf16<<<dim3(TD / 32, TD / 32), blk, 0, stream>>>(Wk, WqkvT + (size_t)TD * TD, TD, TD);
  k_transpose_bf16<<<dim3(TD / 32, TD / 32), blk, 0, stream>>>(Wv, WqkvT + (size_t)2 * TD * TD, TD, TD);
  k_transpose_bf16<<<dim3(TD / 32, TD / 32), blk, 0, stream>>>(Wo, WoT, TD, TD);
  k_transpose_bf16<<<dim3(TFF / 32, TD / 32), blk, 0, stream>>>(W1, W1T, TD, TFF);
  k_transpose_bf16<<<dim3(TD / 32, TFF / 32), blk, 0, stream>>>(W2, W2T, TFF, TD);

  k_addpos<<<(TM * TD / 4 + 255) / 256, blk, 0, stream>>>(x, pos, hB, TM * TD / 4);

  // QKV fused: (4096 x 1024) * (3072 x 1024)^T -> bf16 qkv
  k_gemm<0><<<dim3(TM / 128, 3072 / 128, 1), blk, 0, stream>>>(
      hB, WqkvT, qkv, nullptr, TM, 3072, TD, TD, TD);

  k_vtrans<<<dim3(TB * TH, TS / 64), blk, 0, stream>>>(qkv, vTb);
  k_attn<<<TB * TH * (TS / 64), blk, 0, stream>>>(qkv, vTb, rpe, aoB);

  // Wo: split-K=2 -> two f32 partials
  k_gemm<2><<<dim3(TM / 128, TD / 128, 2), blk, 0, stream>>>(
      aoB, WoT, oF2, nullptr, TM, TD, TD / 2, TD, TD);

  k_ln1<<<TM, blk, 0, stream>>>(x, pos, oF2, oF2 + (size_t)TM * TD, ln1s, ln1o, atF, atB);

  // FFN1: bias+relu -> bf16
  k_gemm<1><<<dim3(TM / 128, TFF / 128, 1), blk, 0, stream>>>(
      atB, W1T, ff1, b1, TM, TFF, TD, TD, TD);

  // FFN2: split-K=2 -> two f32 partials
  k_gemm<2><<<dim3(TM / 128, TD / 128, 2), blk, 0, stream>>>(
      ff1, W2T, ff2, nullptr, TM, TD, TFF / 2, TFF, TFF);

  k_ln2<<<TM, blk, 0, stream>>>(ff2, ff2 + (size_t)TM * TD, atF, b2, ln2s, ln2o,
                                (float*)d_out);
}

// Round 5
// 213.890 us; speedup vs baseline: 2.1686x; 1.0146x over previous
//
#include <hip/hip_runtime.h>
#include <hip/hip_bf16.h>

#define DEVI static __device__ __forceinline__

typedef __attribute__((ext_vector_type(4))) float f32x4;
typedef __attribute__((ext_vector_type(8))) short bf16x8;
typedef __attribute__((ext_vector_type(4))) short s16x4;

constexpr int TB  = 2;      // batch
constexpr int TS  = 2048;   // seq len
constexpr int TD  = 1024;   // model dim
constexpr int TH  = 16;     // heads
constexpr int TDH = 64;     // head dim
constexpr int TC  = 64;     // window size
constexpr int TFF = 4096;   // ffn dim
constexpr int TM  = TB * TS;  // 4096 rows

DEVI float bf2f(short s) {
  return __builtin_bit_cast(float, (unsigned)((unsigned short)s) << 16);
}
DEVI short f2bf(float f) {
  return __builtin_bit_cast(short, __float2bfloat16(f));
}

// async global->LDS, 16B per lane, dest = wave-uniform base + lane*16
#define GLD16(gp, lp)                                              \
  __builtin_amdgcn_global_load_lds(                                \
      (const __attribute__((address_space(1))) void*)(gp),         \
      (__attribute__((address_space(3))) void*)(lp), 16, 0, 0)

// counted vmcnt wait (N = max loads allowed outstanding), compiler-fenced
#define WAITVM(N) asm volatile("s_waitcnt vmcnt(" #N ")" ::: "memory")

// ---------------- weight transpose + f32->bf16 convert --------------------
__global__ __launch_bounds__(256) void k_transpose_bf16(
    const float* __restrict__ W, __hip_bfloat16* __restrict__ WT, int K, int N) {
  __shared__ float tile[32][33];
  int n0 = blockIdx.x * 32, k0 = blockIdx.y * 32;
  int tx = threadIdx.x & 31, ty = threadIdx.x >> 5;  // 32 x 8
  for (int i = 0; i < 32; i += 8)
    tile[ty + i][tx] = W[(size_t)(k0 + ty + i) * N + n0 + tx];
  __syncthreads();
  for (int i = 0; i < 32; i += 8)
    WT[(size_t)(n0 + ty + i) * K + k0 + tx] = __float2bfloat16(tile[tx][ty + i]);
}

// ---------------- h = x + pos[t % C] (bf16 only) --------------------------
__global__ __launch_bounds__(256) void k_addpos(
    const float* __restrict__ x, const float* __restrict__ pos,
    __hip_bfloat16* __restrict__ hb, int total4) {
  int i = blockIdx.x * 256 + threadIdx.x;
  if (i >= total4) return;
  int e = i * 4;
  int d = e & (TD - 1);
  int t = (e / TD) & (TS - 1);
  f32x4 xv = *(const f32x4*)(x + e);
  f32x4 pv = *(const f32x4*)(pos + (size_t)(t & (TC - 1)) * TD + d);
  s16x4 hb4;
  for (int j = 0; j < 4; j++) hb4[j] = f2bf(xv[j] + pv[j]);
  *(s16x4*)((short*)hb + e) = hb4;
}

// ---------------- bf16 MFMA GEMM: 256-M tile, 8 waves, 4-deep pipeline -----
// C = A(MxK) * BT(NxK)^T.  BM=256, BN=256 or 128, BK=32, 512 thr = 8 waves
// (2M x 4N; per-wave 128 x BN/4).  4 LDS dbufs in a ring; prologue stages
// tiles 0..2; iter t: vmcnt(2*LPT) [tiles t+1,t+2 in flight] -> s_barrier ->
// ds_read frags -> stage tile t+3 into dbuf (t+3)&3 -> 2 setprio MFMA
// clusters.  Stage of t+3 is safe: dbuf (t+3)&3's last readers (tile t-1)
// finished (lgkm-waited) before the iter-t barrier that precedes the issue.
// Swizzle (proven 0-conflict r4): LDS slot s of row r holds k-octet
// s^((r>>1)&3); reads xor the same.  EPI: 0 bf16, 1 bias+relu bf16, 2 f32.
template <int BN, int EPI>
__global__ __launch_bounds__(512, 2) void k_gemm2(
    const __hip_bfloat16* __restrict__ A, const __hip_bfloat16* __restrict__ BT,
    void* __restrict__ Cout, const float* __restrict__ bias,
    int M, int N, int K, int lda, int ldb) {
  constexpr int BM = 256, BK = 32;
  constexpr int FN = BN / 64;        // frag cols per wave (4 or 2)
  constexpr int LPB = BN / 128;      // B loads per thread per tile (2 or 1)
  __shared__ __align__(16) short As[4][BM * BK];  // 4 x 16 KB
  __shared__ __align__(16) short Bs[4][BN * BK];  // 4 x (16 or 8) KB
  int tid = threadIdx.x;
  int lane = tid & 63, wave = tid >> 6;
  int wm = wave >> 2, wn = wave & 3;  // 2 x 4 wave grid
  int fr = lane & 15, fg = lane >> 4; // fragment row + k-octet
  int m0 = blockIdx.x * BM, n0 = blockIdx.y * BN;
  size_t koff = (size_t)blockIdx.z * K;
  const __hip_bfloat16* Ab = A + koff;
  const __hip_bfloat16* Bb = BT + koff;

  auto stageA = [&](int d, int T) {
#pragma unroll
    for (int i = 0; i < 2; i++) {
      int c = i * 512 + tid;
      int row = c >> 2, seg = (c & 3) ^ ((row >> 1) & 3);
      GLD16(Ab + (size_t)(m0 + row) * lda + T * BK + seg * 8,
            (char*)&As[d][0] + (i * 512 + wave * 64) * 16);
    }
  };
  auto stageB = [&](int d, int T) {
#pragma unroll
    for (int i = 0; i < LPB; i++) {
      int c = i * 512 + tid;
      int row = c >> 2, seg = (c & 3) ^ ((row >> 1) & 3);
      GLD16(Bb + (size_t)(n0 + row) * ldb + T * BK + seg * 8,
            (char*)&Bs[d][0] + (i * 512 + wave * 64) * 16);
    }
  };

  f32x4 acc[8][FN];
#pragma unroll
  for (int m = 0; m < 8; m++)
#pragma unroll
    for (int n = 0; n < FN; n++) acc[m][n] = f32x4{0.f, 0.f, 0.f, 0.f};

  const int nt = K / BK;  // >= 16 for all our shapes
  stageA(0, 0); stageB(0, 0);
  stageA(1, 1); stageB(1, 1);
  stageA(2, 2); stageB(2, 2);

  for (int t = 0; t < nt; t++) {
    int d = t & 3;
    if (t < nt - 2) {
      if (BN == 256) { WAITVM(8); } else { WAITVM(6); }
    } else if (t == nt - 2) {
      if (BN == 256) { WAITVM(4); } else { WAITVM(3); }
    } else {
      WAITVM(0);
    }
    __builtin_amdgcn_s_barrier();
    asm volatile("" ::: "memory");

    bf16x8 a0[4], bf[FN];
#pragma unroll
    for (int m = 0; m < 4; m++) {
      int row = wm * 128 + m * 16 + fr;
      a0[m] = *(const bf16x8*)((const char*)&As[d][0] + row * 64 +
                               ((fg ^ ((row >> 1) & 3)) << 4));
    }
#pragma unroll
    for (int n = 0; n < FN; n++) {
      int row = wn * (BN / 4) + n * 16 + fr;
      bf[n] = *(const bf16x8*)((const char*)&Bs[d][0] + row * 64 +
                               ((fg ^ ((row >> 1) & 3)) << 4));
    }
    if (t + 3 < nt) stageA((t + 3) & 3, t + 3);
    __builtin_amdgcn_s_setprio(1);
#pragma unroll
    for (int m = 0; m < 4; m++)
#pragma unroll
      for (int n = 0; n < FN; n++)
        acc[m][n] = __builtin_amdgcn_mfma_f32_16x16x32_bf16(a0[m], bf[n],
                                                            acc[m][n], 0, 0, 0);
    __builtin_amdgcn_s_setprio(0);

    bf16x8 a1[4];
#pragma unroll
    for (int m = 0; m < 4; m++) {
      int row = wm * 128 + 64 + m * 16 + fr;
      a1[m] = *(const bf16x8*)((const char*)&As[d][0] + row * 64 +
                               ((fg ^ ((row >> 1) & 3)) << 4));
    }
    if (t + 3 < nt) stageB((t + 3) & 3, t + 3);
    __builtin_amdgcn_s_setprio(1);
#pragma unroll
    for (int m = 0; m < 4; m++)
#pragma unroll
      for (int n = 0; n < FN; n++)
        acc[m + 4][n] = __builtin_amdgcn_mfma_f32_16x16x32_bf16(a1[m], bf[n],
                                                                acc[m + 4][n], 0, 0, 0);
    __builtin_amdgcn_s_setprio(0);
  }

  float* Cf = (float*)Cout + (size_t)blockIdx.z * M * N;
#pragma unroll
  for (int m = 0; m < 8; m++)
#pragma unroll
    for (int n = 0; n < FN; n++) {
      int col = n0 + wn * (BN / 4) + n * 16 + fr;
      float bv = (EPI == 1) ? bias[col] : 0.f;
#pragma unroll
      for (int j = 0; j < 4; j++) {
        int row = m0 + wm * 128 + m * 16 + fg * 4 + j;
        float v = acc[m][n][j];
        if (EPI == 1) { v += bv; v = fmaxf(v, 0.f); }
        if (EPI == 2)
          Cf[(size_t)row * N + col] = v;
        else
          ((__hip_bfloat16*)Cout)[(size_t)row * N + col] = __float2bfloat16(v);
      }
    }
}

// ---------------- V transpose: qkv v-slice -> vT[bh][64 d][2048 t] --------
__global__ __launch_bounds__(256) void k_vtrans(
    const __hip_bfloat16* __restrict__ qkv, __hip_bfloat16* __restrict__ vT) {
  __shared__ short tile[64][68];  // [t][d], pad->136B row stride
  int bh = blockIdx.x;            // b*16+h
  int tb = blockIdx.y;            // 64-row t block
  int b = bh >> 4, h = bh & 15;
  int tid = threadIdx.x;
#pragma unroll
  for (int i = 0; i < 2; i++) {
    int c = i * 256 + tid;        // 512 chunks of 8 elems
    int trow = c >> 3, seg = c & 7;
    bf16x8 v = *(const bf16x8*)((const short*)qkv +
        (size_t)(b * TS + tb * 64 + trow) * 3072 + 2048 + h * TDH + seg * 8);
    s16x4 lo = {v[0], v[1], v[2], v[3]}, hi = {v[4], v[5], v[6], v[7]};
    *(s16x4*)&tile[trow][seg * 8] = lo;
    *(s16x4*)&tile[trow][seg * 8 + 4] = hi;
  }
  __syncthreads();
#pragma unroll
  for (int i2 = 0; i2 < 2; i2++) {
    int c = i2 * 256 + tid;
    int d = c >> 3, ts = c & 7;   // output row d, t-chunk ts
    bf16x8 o;
#pragma unroll
    for (int j = 0; j < 8; j++) o[j] = tile[ts * 8 + j][d];
    *(bf16x8*)((short*)vT + (size_t)bh * TDH * TS + (size_t)d * TS +
               tb * 64 + ts * 8) = o;
  }
}

// ---------------- sliding-window attention (MFMA) --------------------------
__global__ __launch_bounds__(256) void k_attn(
    const __hip_bfloat16* __restrict__ qkv, const __hip_bfloat16* __restrict__ vT,
    const float* __restrict__ rpe, __hip_bfloat16* __restrict__ out) {
  __shared__ __align__(16) short K_lds[128 * 64];    // [jj][64k], swz
  __shared__ __align__(16) short VT_lds[64 * 128];   // [d][128jj], swz
  __shared__ __align__(16) short P_lds[4][16 * 136]; // per-wave [q][jj], pad
  __shared__ float rpe_lds[TC];
  int tid = threadIdx.x, lane = tid & 63, wave = tid >> 6;
  int fr = lane & 15, g = lane >> 4;
  int blk = blockIdx.x;           // (b*16+h)*32 + qt
  int qt = blk & 31, bh = blk >> 5;
  int h = bh & 15, b = bh >> 4;
  int t0 = qt * 64;
  const short* qg = (const short*)qkv;

  if (tid < TC) rpe_lds[tid] = rpe[h * TC + tid];

#pragma unroll
  for (int i = 0; i < 4; i++) {
    int cb = i * 256 + wave * 64;
    int c = cb + lane;
    int row = c >> 3, slot = c & 7;
    int seg = slot ^ (row & 7);
    int kr = t0 - 64 + row; if (kr < 0) kr = 0;
    GLD16(qg + ((size_t)(b * TS + kr) * 3072 + 1024 + h * TDH + seg * 8),
          (char*)K_lds + cb * 16);
  }
  const short* vg = (const short*)vT + (size_t)bh * TDH * TS;
#pragma unroll
  for (int i = 0; i < 4; i++) {
    int cb = i * 256 + wave * 64;
    int c = cb + lane;
    int row = c >> 4, slot = c & 15;
    int seg = slot ^ (row & 15);
    int tc = t0 - 64 + seg * 8; if (tc < 0) tc = 0;
    GLD16(vg + (size_t)row * TS + tc, (char*)VT_lds + cb * 16);
  }

  int qrow = t0 + wave * 16 + fr;
  const short* qptr = qg + ((size_t)(b * TS + qrow) * 3072 + h * TDH + g * 8);
  bf16x8 qf0 = *(const bf16x8*)qptr;
  bf16x8 qf1 = *(const bf16x8*)(qptr + 32);

  __syncthreads();  // drains GLD16 (vmcnt) + barrier

  f32x4 S[8] = {};
#pragma unroll
  for (int kk = 0; kk < 2; kk++) {
    bf16x8 a = kk ? qf1 : qf0;
#pragma unroll
    for (int nt = 0; nt < 8; nt++) {
      int row = nt * 16 + fr;
      int slot = (kk * 4 + g) ^ (row & 7);
      bf16x8 bfrag = *(const bf16x8*)((const char*)K_lds + row * 128 + slot * 16);
      S[nt] = __builtin_amdgcn_mfma_f32_16x16x32_bf16(a, bfrag, S[nt], 0, 0, 0);
    }
  }

  int wq = wave * 16;
#pragma unroll
  for (int r = 0; r < 4; r++) {
    int ql = g * 4 + r;
    float sc[8];
    float m = -3.4028235e38f;
#pragma unroll
    for (int nt = 0; nt < 8; nt++) {
      int jj = nt * 16 + fr;
      int d = wq + ql + 64 - jj;
      bool valid = (d >= 0) && (d < TC) && (t0 - 64 + jj >= 0);
      float v = valid ? (S[nt][r] * 0.125f + rpe_lds[d & (TC - 1)])
                      : -3.4028235e38f;
      sc[nt] = v;
      m = fmaxf(m, v);
    }
#pragma unroll
    for (int o = 1; o < 16; o <<= 1) m = fmaxf(m, __shfl_xor(m, o));
    float p[8], sum = 0.f;
#pragma unroll
    for (int nt = 0; nt < 8; nt++) { p[nt] = __expf(sc[nt] - m); sum += p[nt]; }
#pragma unroll
    for (int o = 1; o < 16; o <<= 1) sum += __shfl_xor(sum, o);
    float rs = 1.0f / sum;
#pragma unroll
    for (int nt = 0; nt < 8; nt++)
      P_lds[wave][ql * 136 + nt * 16 + fr] = f2bf(p[nt] * rs);
  }

  f32x4 O[4] = {};
#pragma unroll
  for (int kk = 0; kk < 4; kk++) {
    bf16x8 pa = *(const bf16x8*)((const char*)&P_lds[wave][0] +
                                 fr * 272 + kk * 64 + g * 16);
#pragma unroll
    for (int dt = 0; dt < 4; dt++) {
      int row = dt * 16 + fr;
      int slot = (kk * 4 + g) ^ (row & 15);
      bf16x8 vb = *(const bf16x8*)((const char*)VT_lds + row * 256 + slot * 16);
      O[dt] = __builtin_amdgcn_mfma_f32_16x16x32_bf16(pa, vb, O[dt], 0, 0, 0);
    }
  }

  size_t ob = ((size_t)(b * TS + t0 + wq + g * 4)) * TD + h * TDH;
#pragma unroll
  for (int dt = 0; dt < 4; dt++)
#pragma unroll
    for (int r = 0; r < 4; r++)
      ((short*)out)[ob + (size_t)r * TD + dt * 16 + fr] = f2bf(O[dt][r]);
}

// ---------------- LayerNorm (two-pass, fused residual + split-K sum) ------
DEVI float block_sum(float v, float* red) {
  for (int o = 32; o; o >>= 1) v += __shfl_xor(v, o);
  int wave = threadIdx.x >> 6;
  if ((threadIdx.x & 63) == 0) red[wave] = v;
  __syncthreads();
  float r = red[0] + red[1] + red[2] + red[3];
  __syncthreads();
  return r;
}

__global__ __launch_bounds__(256) void k_ln1(
    const float* __restrict__ x, const float* __restrict__ pos,
    const float* __restrict__ P0, const float* __restrict__ P1,
    const float* __restrict__ scale, const float* __restrict__ offset,
    float* __restrict__ outf, __hip_bfloat16* __restrict__ outb) {
  __shared__ float red[4];
  int row = blockIdx.x, tid = threadIdx.x;
  int t = row & (TS - 1), pr = t & (TC - 1);
  size_t base = (size_t)row * TD + tid * 4;
  f32x4 xv = *(const f32x4*)(x + base);
  f32x4 pv = *(const f32x4*)(pos + (size_t)pr * TD + tid * 4);
  f32x4 a0 = *(const f32x4*)(P0 + base);
  f32x4 a1 = *(const f32x4*)(P1 + base);
  xv = xv + pv + a0 + a1;
  float s = xv[0] + xv[1] + xv[2] + xv[3];
  s = block_sum(s, red);
  float mu = s * (1.f / TD);
  float s2 = 0.f;
  for (int j = 0; j < 4; j++) { float dlt = xv[j] - mu; s2 += dlt * dlt; }
  s2 = block_sum(s2, red);
  float rs = rsqrtf(s2 * (1.f / TD) + 1e-5f);
  f32x4 sc = *(const f32x4*)(scale + tid * 4);
  f32x4 of = *(const f32x4*)(offset + tid * 4);
  f32x4 y;
  for (int j = 0; j < 4; j++) y[j] = (xv[j] - mu) * rs * sc[j] + of[j];
  *(f32x4*)(outf + base) = y;
  s16x4 pb;
  for (int j = 0; j < 4; j++) pb[j] = f2bf(y[j]);
  *(s16x4*)((short*)outb + base) = pb;
}

__global__ __launch_bounds__(256) void k_ln2(
    const float* __restrict__ P0, const float* __restrict__ P1,
    const float* __restrict__ R, const float* __restrict__ bias,
    const float* __restrict__ scale, const float* __restrict__ offset,
    float* __restrict__ outf) {
  __shared__ float red[4];
  int row = blockIdx.x, tid = threadIdx.x;
  size_t base = (size_t)row * TD + tid * 4;
  f32x4 a0 = *(const f32x4*)(P0 + base);
  f32x4 a1 = *(const f32x4*)(P1 + base);
  f32x4 rv = *(const f32x4*)(R + base);
  f32x4 bi = *(const f32x4*)(bias + tid * 4);
  f32x4 xv = a0 + a1 + rv + bi;
  float s = xv[0] + xv[1] + xv[2] + xv[3];
  s = block_sum(s, red);
  float mu = s * (1.f / TD);
  float s2 = 0.f;
  for (int j = 0; j < 4; j++) { float dlt = xv[j] - mu; s2 += dlt * dlt; }
  s2 = block_sum(s2, red);
  float rs = rsqrtf(s2 * (1.f / TD) + 1e-5f);
  f32x4 sc = *(const f32x4*)(scale + tid * 4);
  f32x4 of = *(const f32x4*)(offset + tid * 4);
  f32x4 y;
  for (int j = 0; j < 4; j++) y[j] = (xv[j] - mu) * rs * sc[j] + of[j];
  *(f32x4*)(outf + base) = y;
}

// --------------------------------------------------------------------------
extern "C" void kernel_launch(void* const* d_in, const int* in_sizes, int n_in,
                              void* d_out, int out_size, void* d_ws, size_t ws_size,
                              hipStream_t stream) {
  const float* x    = (const float*)d_in[0];
  const float* pos  = (const float*)d_in[2];
  const float* rpe  = (const float*)d_in[3];
  const float* Wq   = (const float*)d_in[4];
  const float* Wk   = (const float*)d_in[5];
  const float* Wv   = (const float*)d_in[6];
  const float* Wo   = (const float*)d_in[7];
  const float* ln1s = (const float*)d_in[8];
  const float* ln1o = (const float*)d_in[9];
  const float* W1   = (const float*)d_in[10];
  const float* b1   = (const float*)d_in[11];
  const float* W2   = (const float*)d_in[12];
  const float* b2   = (const float*)d_in[13];
  const float* ln2s = (const float*)d_in[14];
  const float* ln2o = (const float*)d_in[15];

  char* ws = (char*)d_ws;
  const size_t MB = 1ull << 20;
  __hip_bfloat16* WqkvT = (__hip_bfloat16*)(ws + 0 * MB);   // 6 MB
  __hip_bfloat16* WoT   = (__hip_bfloat16*)(ws + 6 * MB);   // 2 MB
  __hip_bfloat16* W1T   = (__hip_bfloat16*)(ws + 8 * MB);   // 8 MB
  __hip_bfloat16* W2T   = (__hip_bfloat16*)(ws + 16 * MB);  // 8 MB
  __hip_bfloat16* hB    = (__hip_bfloat16*)(ws + 24 * MB);  // 8 MB (dead after QKV)
  __hip_bfloat16* qkv   = (__hip_bfloat16*)(ws + 32 * MB);  // 24 MB (dead after attn)
  __hip_bfloat16* aoB   = (__hip_bfloat16*)(ws + 56 * MB);  // 8 MB (dead after Wo)
  float*          oF2   = (float*)(ws + 64 * MB);           // 32 MB (dead after ln1)
  float*          atF   = (float*)(ws + 96 * MB);           // 16 MB
  __hip_bfloat16* atB   = (__hip_bfloat16*)(ws + 24 * MB);  // 8 MB (aliases hB)
  __hip_bfloat16* ff1   = (__hip_bfloat16*)(ws + 32 * MB);  // 32 MB (aliases qkv+aoB)
  float*          ff2   = (float*)(ws + 64 * MB);           // 32 MB (aliases oF2)
  __hip_bfloat16* vTb   = (__hip_bfloat16*)(ws + 112 * MB); // 8 MB (dead after attn)
  // high-water: 120 MB

  dim3 blk(256), blk5(512);

  k_transpose_bf16<<<dim3(TD / 32, TD / 32), blk, 0, stream>>>(Wq, WqkvT, TD, TD);
  k_transpose_bf16<<<dim3(TD / 32, TD / 32), blk, 0, stream>>>(Wk, WqkvT + (size_t)TD * TD, TD, TD);
  k_transpose_bf16<<<dim3(TD / 32, TD / 32), blk, 0, stream>>>(Wv, WqkvT + (size_t)2 * TD * TD, TD, TD);
  k_transpose_bf16<<<dim3(TD / 32, TD / 32), blk, 0, stream>>>(Wo, WoT, TD, TD);
  k_transpose_bf16<<<dim3(TFF / 32, TD / 32), blk, 0, stream>>>(W1, W1T, TD, TFF);
  k_transpose_bf16<<<dim3(TD / 32, TFF / 32), blk, 0, stream>>>(W2, W2T, TFF, TD);

  k_addpos<<<(TM * TD / 4 + 255) / 256, blk, 0, stream>>>(x, pos, hB, TM * TD / 4);

  // QKV fused: (4096 x 1024) * (3072 x 1024)^T -> bf16 qkv
  k_gemm2<256, 0><<<dim3(TM / 256, 3072 / 256, 1), blk5, 0, stream>>>(
      hB, WqkvT, qkv, nullptr, TM, 3072, TD, TD, TD);

  k_vtrans<<<dim3(TB * TH, TS / 64), blk, 0, stream>>>(qkv, vTb);
  k_attn<<<TB * TH * (TS / 64), blk, 0, stream>>>(qkv, vTb, rpe, aoB);

  // Wo: BN=128, split-K=2 -> two f32 partials (grid 16x8x2 = 256 blocks)
  k_gemm2<128, 2><<<dim3(TM / 256, TD / 128, 2), blk5, 0, stream>>>(
      aoB, WoT, oF2, nullptr, TM, TD, TD / 2, TD, TD);

  k_ln1<<<TM, blk, 0, stream>>>(x, pos, oF2, oF2 + (size_t)TM * TD, ln1s, ln1o, atF, atB);

  // FFN1: bias+relu -> bf16 (grid 16x16 = 256 blocks)
  k_gemm2<256, 1><<<dim3(TM / 256, TFF / 256, 1), blk5, 0, stream>>>(
      atB, W1T, ff1, b1, TM, TFF, TD, TD, TD);

  // FFN2: BN=128, split-K=2 -> two f32 partials (grid 16x8x2 = 256 blocks)
  k_gemm2<128, 2><<<dim3(TM / 256, TD / 128, 2), blk5, 0, stream>>>(
      ff1, W2T, ff2, nullptr, TM, TD, TFF / 2, TFF, TFF);

  k_ln2<<<TM, blk, 0, stream>>>(ff2, ff2 + (size_t)TM * TD, atF, b2, ln2s, ln2o,
                                (float*)d_out);
}

// Round 6
// 204.856 us; speedup vs baseline: 2.2643x; 1.0441x over previous
//
#include <hip/hip_runtime.h>
#include <hip/hip_bf16.h>

#define DEVI static __device__ __forceinline__

typedef __attribute__((ext_vector_type(4))) float f32x4;
typedef __attribute__((ext_vector_type(8))) short bf16x8;
typedef __attribute__((ext_vector_type(4))) short s16x4;

constexpr int TB  = 2;      // batch
constexpr int TS  = 2048;   // seq len
constexpr int TD  = 1024;   // model dim
constexpr int TH  = 16;     // heads
constexpr int TDH = 64;     // head dim
constexpr int TC  = 64;     // window size
constexpr int TFF = 4096;   // ffn dim
constexpr int TM  = TB * TS;  // 4096 rows

DEVI float bf2f(short s) {
  return __builtin_bit_cast(float, (unsigned)((unsigned short)s) << 16);
}
DEVI short f2bf(float f) {
  return __builtin_bit_cast(short, __float2bfloat16(f));
}

// async global->LDS, 16B per lane, dest = wave-uniform base + lane*16
#define GLD16(gp, lp)                                              \
  __builtin_amdgcn_global_load_lds(                                \
      (const __attribute__((address_space(1))) void*)(gp),         \
      (__attribute__((address_space(3))) void*)(lp), 16, 0, 0)

// counted vmcnt wait (N = max loads allowed outstanding), compiler-fenced
#define WAITVM(N) asm volatile("s_waitcnt vmcnt(" #N ")" ::: "memory")

// ---------------- all weight transposes in ONE dispatch -------------------
// W (K x N) f32 row-major -> WT (N x K) bf16 row-major, 32x32 tiles
__global__ __launch_bounds__(256) void k_trans_all(
    const float* __restrict__ Wq, const float* __restrict__ Wk,
    const float* __restrict__ Wv, const float* __restrict__ Wo,
    const float* __restrict__ W1, const float* __restrict__ W2,
    __hip_bfloat16* __restrict__ WqkvT, __hip_bfloat16* __restrict__ WoT,
    __hip_bfloat16* __restrict__ W1T, __hip_bfloat16* __restrict__ W2T) {
  __shared__ float tile[32][33];
  int bid = blockIdx.x;
  const float* src; __hip_bfloat16* dst;
  int K, N, n0, k0;
  if (bid < 4096) {                      // Wq,Wk,Wv,Wo : 1024x1024 each
    int m = bid >> 10, t = bid & 1023;
    src = (m == 0) ? Wq : (m == 1) ? Wk : (m == 2) ? Wv : Wo;
    dst = (m == 3) ? WoT : WqkvT + (size_t)m * TD * TD;
    K = TD; N = TD; n0 = (t & 31) * 32; k0 = (t >> 5) * 32;
  } else if (bid < 8192) {               // W1 : 1024x4096
    int t = bid - 4096;
    src = W1; dst = W1T; K = TD; N = TFF;
    n0 = (t & 127) * 32; k0 = (t >> 7) * 32;
  } else {                               // W2 : 4096x1024
    int t = bid - 8192;
    src = W2; dst = W2T; K = TFF; N = TD;
    n0 = (t & 31) * 32; k0 = (t >> 5) * 32;
  }
  int tx = threadIdx.x & 31, ty = threadIdx.x >> 5;  // 32 x 8
  for (int i = 0; i < 32; i += 8)
    tile[ty + i][tx] = src[(size_t)(k0 + ty + i) * N + n0 + tx];
  __syncthreads();
  for (int i = 0; i < 32; i += 8)
    dst[(size_t)(n0 + ty + i) * K + k0 + tx] = __float2bfloat16(tile[tx][ty + i]);
}

// ---------------- h = x + pos[t % C] (bf16 only) --------------------------
__global__ __launch_bounds__(256) void k_addpos(
    const float* __restrict__ x, const float* __restrict__ pos,
    __hip_bfloat16* __restrict__ hb, int total4) {
  int i = blockIdx.x * 256 + threadIdx.x;
  if (i >= total4) return;
  int e = i * 4;
  int d = e & (TD - 1);
  int t = (e / TD) & (TS - 1);
  f32x4 xv = *(const f32x4*)(x + e);
  f32x4 pv = *(const f32x4*)(pos + (size_t)(t & (TC - 1)) * TD + d);
  s16x4 hb4;
  for (int j = 0; j < 4; j++) hb4[j] = f2bf(xv[j] + pv[j]);
  *(s16x4*)((short*)hb + e) = hb4;
}

// ---------------- bf16 MFMA GEMM: 8-phase-style, ring-4, counted vmcnt ----
// C = A(MxK) * BT(NxK)^T.  BM=256, BK=32, 512 thr = 8 waves (2M x 4N),
// per-wave C = 128 x (BN/4).  Ring of 4 LDS tile-buffers; stage of tile t+3
// (issued during tile t) targets buf (t+3)&3, which no wave touches during
// tiles t-1..t+2 -> race-free by construction.  Phases of 16 MFMA with TWO
// raw barriers each (m196 structure); vmcnt(8/6) once per tile in its last
// phase guarantees tile t+1 in LDS after that phase's barrier; loads keep
// 2 tiles in flight, never drained in steady state (T4).  T5 setprio around
// MFMA clusters.  Swizzle: LDS slot s of row r holds k-octet s^((r>>1)&3)
// (proven 0-conflict, r4/r5).
// BN=256: 2 phases/tile (m-halves; B-frags reused).  BN=128: 1 phase/tile.
// EPI: 0 = store bf16, 1 = bias+relu bf16, 2 = f32 split-K partial.
template <int BN, int EPI>
__global__ __launch_bounds__(512, 2) void k_gemm8(
    const __hip_bfloat16* __restrict__ A, const __hip_bfloat16* __restrict__ BT,
    void* __restrict__ Cout, const float* __restrict__ bias,
    int M, int N, int K, int lda, int ldb) {
  constexpr int BM = 256, BK = 32;
  constexpr int FN = BN / 64;                  // n-frags per wave: 4 or 2
  __shared__ __align__(16) short As[4][BM * BK];  // 4 x 16 KB
  __shared__ __align__(16) short Bs[4][BN * BK];  // 4 x (16 | 8) KB
  int tid = threadIdx.x, lane = tid & 63, wave = tid >> 6;
  int wm = wave >> 2, wn = wave & 3;           // 2 x 4 wave grid
  int fr = lane & 15, fg = lane >> 4;
  int m0 = blockIdx.x * BM, n0 = blockIdx.y * BN;
  size_t koff = (size_t)blockIdx.z * K;
  const short* Ab = (const short*)A + koff;
  const short* Bb = (const short*)BT + koff;

  // per-thread staging source pointers; tile T advances by T*BK shorts
  int r0 = tid >> 2, s0 = (tid & 3) ^ ((r0 >> 1) & 3);
  int r1 = 128 + r0, s1 = (tid & 3) ^ ((r1 >> 1) & 3);
  const short* pA0 = Ab + (size_t)(m0 + r0) * lda + s0 * 8;
  const short* pA1 = Ab + (size_t)(m0 + r1) * lda + s1 * 8;
  const short* pB0 = Bb + (size_t)(n0 + r0) * ldb + s0 * 8;
  const short* pB1 = (BN == 256) ? Bb + (size_t)(n0 + r1) * ldb + s1 * 8 : pB0;
  int dst0 = (wave * 64) * 16;                 // LDS byte offsets
  int dst1 = (512 + wave * 64) * 16;

  auto stageA = [&](int d, int T) {
    GLD16(pA0 + T * BK, (char*)&As[d][0] + dst0);
    GLD16(pA1 + T * BK, (char*)&As[d][0] + dst1);
  };
  auto stageB = [&](int d, int T) {
    GLD16(pB0 + T * BK, (char*)&Bs[d][0] + dst0);
    if constexpr (BN == 256) GLD16(pB1 + T * BK, (char*)&Bs[d][0] + dst1);
  };

  f32x4 acc[8][FN];
#pragma unroll
  for (int m = 0; m < 8; m++)
#pragma unroll
    for (int n = 0; n < FN; n++) acc[m][n] = f32x4{0.f, 0.f, 0.f, 0.f};

  const int nt = K / BK;  // >= 16 for all shapes used
  stageA(0, 0); stageB(0, 0);
  stageA(1, 1); stageB(1, 1);
  stageA(2, 2); stageB(2, 2);
  if (BN == 256) { WAITVM(8); } else { WAITVM(6); }  // tile 0 landed; 1,2 in flight
  __builtin_amdgcn_s_barrier();

  for (int t = 0; t < nt; t++) {
    int d = t & 3, pf = (t + 3) & 3;
    bool dopf = (t + 3) < nt;
    const char* Al = (const char*)&As[d][0];
    const char* Bl = (const char*)&Bs[d][0];
    if constexpr (BN == 256) {
      bf16x8 a[4], b[4];
      // ---- phase 0: m-half 0, load B frags (reused in phase 1) ----
#pragma unroll
      for (int mt = 0; mt < 4; mt++) {
        int row = wm * 128 + mt * 16 + fr;
        a[mt] = *(const bf16x8*)(Al + row * 64 + ((fg ^ ((row >> 1) & 3)) << 4));
      }
#pragma unroll
      for (int n = 0; n < 4; n++) {
        int row = wn * 64 + n * 16 + fr;
        b[n] = *(const bf16x8*)(Bl + row * 64 + ((fg ^ ((row >> 1) & 3)) << 4));
      }
      if (dopf) stageA(pf, t + 3);
      __builtin_amdgcn_s_barrier();
      __builtin_amdgcn_s_setprio(1);
#pragma unroll
      for (int mt = 0; mt < 4; mt++)
#pragma unroll
        for (int n = 0; n < 4; n++)
          acc[mt][n] = __builtin_amdgcn_mfma_f32_16x16x32_bf16(a[mt], b[n],
                                                               acc[mt][n], 0, 0, 0);
      __builtin_amdgcn_s_setprio(0);
      __builtin_amdgcn_s_barrier();
      // ---- phase 1: m-half 1 ----
#pragma unroll
      for (int mt = 0; mt < 4; mt++) {
        int row = wm * 128 + 64 + mt * 16 + fr;
        a[mt] = *(const bf16x8*)(Al + row * 64 + ((fg ^ ((row >> 1) & 3)) << 4));
      }
      if (dopf) stageB(pf, t + 3);
      if (t < nt - 3) { WAITVM(8); }
      else if (t == nt - 3) { WAITVM(4); }
      else if (t == nt - 2) { WAITVM(0); }
      __builtin_amdgcn_s_barrier();
      __builtin_amdgcn_s_setprio(1);
#pragma unroll
      for (int mt = 0; mt < 4; mt++)
#pragma unroll
        for (int n = 0; n < 4; n++)
          acc[4 + mt][n] = __builtin_amdgcn_mfma_f32_16x16x32_bf16(a[mt], b[n],
                                                                   acc[4 + mt][n], 0, 0, 0);
      __builtin_amdgcn_s_setprio(0);
      __builtin_amdgcn_s_barrier();
    } else {
      // ---- single phase: full 128x32 wave-C over K=32 ----
      bf16x8 a[8], b[2];
#pragma unroll
      for (int mt = 0; mt < 8; mt++) {
        int row = wm * 128 + mt * 16 + fr;
        a[mt] = *(const bf16x8*)(Al + row * 64 + ((fg ^ ((row >> 1) & 3)) << 4));
      }
#pragma unroll
      for (int n = 0; n < 2; n++) {
        int row = wn * 32 + n * 16 + fr;
        b[n] = *(const bf16x8*)(Bl + row * 64 + ((fg ^ ((row >> 1) & 3)) << 4));
      }
      if (dopf) { stageA(pf, t + 3); stageB(pf, t + 3); }
      if (t < nt - 3) { WAITVM(6); }
      else if (t == nt - 3) { WAITVM(3); }
      else if (t == nt - 2) { WAITVM(0); }
      __builtin_amdgcn_s_barrier();
      __builtin_amdgcn_s_setprio(1);
#pragma unroll
      for (int mt = 0; mt < 8; mt++)
#pragma unroll
        for (int n = 0; n < 2; n++)
          acc[mt][n] = __builtin_amdgcn_mfma_f32_16x16x32_bf16(a[mt], b[n],
                                                               acc[mt][n], 0, 0, 0);
      __builtin_amdgcn_s_setprio(0);
      __builtin_amdgcn_s_barrier();
    }
  }

  float* Cf = (float*)Cout + (size_t)blockIdx.z * M * N;
#pragma unroll
  for (int mt = 0; mt < 8; mt++)
#pragma unroll
    for (int n = 0; n < FN; n++) {
      int col = n0 + wn * (BN / 4) + n * 16 + fr;
      float bv = (EPI == 1) ? bias[col] : 0.f;
#pragma unroll
      for (int j = 0; j < 4; j++) {
        int row = m0 + wm * 128 + mt * 16 + fg * 4 + j;
        float v = acc[mt][n][j];
        if (EPI == 1) { v += bv; v = fmaxf(v, 0.f); }
        if (EPI == 2)
          Cf[(size_t)row * N + col] = v;
        else
          ((__hip_bfloat16*)Cout)[(size_t)row * N + col] = __float2bfloat16(v);
      }
    }
}

// ---------------- V transpose: qkv v-slice -> vT[bh][64 d][2048 t] --------
__global__ __launch_bounds__(256) void k_vtrans(
    const __hip_bfloat16* __restrict__ qkv, __hip_bfloat16* __restrict__ vT) {
  __shared__ short tile[64][68];  // [t][d], pad->136B row stride
  int bh = blockIdx.x;            // b*16+h
  int tb = blockIdx.y;            // 64-row t block
  int b = bh >> 4, h = bh & 15;
  int tid = threadIdx.x;
#pragma unroll
  for (int i = 0; i < 2; i++) {
    int c = i * 256 + tid;        // 512 chunks of 8 elems
    int trow = c >> 3, seg = c & 7;
    bf16x8 v = *(const bf16x8*)((const short*)qkv +
        (size_t)(b * TS + tb * 64 + trow) * 3072 + 2048 + h * TDH + seg * 8);
    s16x4 lo = {v[0], v[1], v[2], v[3]}, hi = {v[4], v[5], v[6], v[7]};
    *(s16x4*)&tile[trow][seg * 8] = lo;
    *(s16x4*)&tile[trow][seg * 8 + 4] = hi;
  }
  __syncthreads();
#pragma unroll
  for (int i2 = 0; i2 < 2; i2++) {
    int c = i2 * 256 + tid;
    int d = c >> 3, ts = c & 7;   // output row d, t-chunk ts
    bf16x8 o;
#pragma unroll
    for (int j = 0; j < 8; j++) o[j] = tile[ts * 8 + j][d];
    *(bf16x8*)((short*)vT + (size_t)bh * TDH * TS + (size_t)d * TS +
               tb * 64 + ts * 8) = o;
  }
}

// ---------------- sliding-window attention (MFMA) --------------------------
__global__ __launch_bounds__(256) void k_attn(
    const __hip_bfloat16* __restrict__ qkv, const __hip_bfloat16* __restrict__ vT,
    const float* __restrict__ rpe, __hip_bfloat16* __restrict__ out) {
  __shared__ __align__(16) short K_lds[128 * 64];    // [jj][64k], swz
  __shared__ __align__(16) short VT_lds[64 * 128];   // [d][128jj], swz
  __shared__ __align__(16) short P_lds[4][16 * 136]; // per-wave [q][jj], pad
  __shared__ float rpe_lds[TC];
  int tid = threadIdx.x, lane = tid & 63, wave = tid >> 6;
  int fr = lane & 15, g = lane >> 4;
  int blk = blockIdx.x;           // (b*16+h)*32 + qt
  int qt = blk & 31, bh = blk >> 5;
  int h = bh & 15, b = bh >> 4;
  int t0 = qt * 64;
  const short* qg = (const short*)qkv;

  if (tid < TC) rpe_lds[tid] = rpe[h * TC + tid];

#pragma unroll
  for (int i = 0; i < 4; i++) {
    int cb = i * 256 + wave * 64;
    int c = cb + lane;
    int row = c >> 3, slot = c & 7;
    int seg = slot ^ (row & 7);
    int kr = t0 - 64 + row; if (kr < 0) kr = 0;
    GLD16(qg + ((size_t)(b * TS + kr) * 3072 + 1024 + h * TDH + seg * 8),
          (char*)K_lds + cb * 16);
  }
  const short* vg = (const short*)vT + (size_t)bh * TDH * TS;
#pragma unroll
  for (int i = 0; i < 4; i++) {
    int cb = i * 256 + wave * 64;
    int c = cb + lane;
    int row = c >> 4, slot = c & 15;
    int seg = slot ^ (row & 15);
    int tc = t0 - 64 + seg * 8; if (tc < 0) tc = 0;
    GLD16(vg + (size_t)row * TS + tc, (char*)VT_lds + cb * 16);
  }

  int qrow = t0 + wave * 16 + fr;
  const short* qptr = qg + ((size_t)(b * TS + qrow) * 3072 + h * TDH + g * 8);
  bf16x8 qf0 = *(const bf16x8*)qptr;
  bf16x8 qf1 = *(const bf16x8*)(qptr + 32);

  __syncthreads();  // drains GLD16 (vmcnt) + barrier

  f32x4 S[8] = {};
#pragma unroll
  for (int kk = 0; kk < 2; kk++) {
    bf16x8 a = kk ? qf1 : qf0;
#pragma unroll
    for (int nt = 0; nt < 8; nt++) {
      int row = nt * 16 + fr;
      int slot = (kk * 4 + g) ^ (row & 7);
      bf16x8 bfrag = *(const bf16x8*)((const char*)K_lds + row * 128 + slot * 16);
      S[nt] = __builtin_amdgcn_mfma_f32_16x16x32_bf16(a, bfrag, S[nt], 0, 0, 0);
    }
  }

  int wq = wave * 16;
#pragma unroll
  for (int r = 0; r < 4; r++) {
    int ql = g * 4 + r;
    float sc[8];
    float m = -3.4028235e38f;
#pragma unroll
    for (int nt = 0; nt < 8; nt++) {
      int jj = nt * 16 + fr;
      int d = wq + ql + 64 - jj;
      bool valid = (d >= 0) && (d < TC) && (t0 - 64 + jj >= 0);
      float v = valid ? (S[nt][r] * 0.125f + rpe_lds[d & (TC - 1)])
                      : -3.4028235e38f;
      sc[nt] = v;
      m = fmaxf(m, v);
    }
#pragma unroll
    for (int o = 1; o < 16; o <<= 1) m = fmaxf(m, __shfl_xor(m, o));
    float p[8], sum = 0.f;
#pragma unroll
    for (int nt = 0; nt < 8; nt++) { p[nt] = __expf(sc[nt] - m); sum += p[nt]; }
#pragma unroll
    for (int o = 1; o < 16; o <<= 1) sum += __shfl_xor(sum, o);
    float rs = 1.0f / sum;
#pragma unroll
    for (int nt = 0; nt < 8; nt++)
      P_lds[wave][ql * 136 + nt * 16 + fr] = f2bf(p[nt] * rs);
  }

  f32x4 O[4] = {};
#pragma unroll
  for (int kk = 0; kk < 4; kk++) {
    bf16x8 pa = *(const bf16x8*)((const char*)&P_lds[wave][0] +
                                 fr * 272 + kk * 64 + g * 16);
#pragma unroll
    for (int dt = 0; dt < 4; dt++) {
      int row = dt * 16 + fr;
      int slot = (kk * 4 + g) ^ (row & 15);
      bf16x8 vb = *(const bf16x8*)((const char*)VT_lds + row * 256 + slot * 16);
      O[dt] = __builtin_amdgcn_mfma_f32_16x16x32_bf16(pa, vb, O[dt], 0, 0, 0);
    }
  }

  size_t ob = ((size_t)(b * TS + t0 + wq + g * 4)) * TD + h * TDH;
#pragma unroll
  for (int dt = 0; dt < 4; dt++)
#pragma unroll
    for (int r = 0; r < 4; r++)
      ((short*)out)[ob + (size_t)r * TD + dt * 16 + fr] = f2bf(O[dt][r]);
}

// ---------------- LayerNorm (two-pass, fused residual + split-K sum) ------
DEVI float block_sum(float v, float* red) {
  for (int o = 32; o; o >>= 1) v += __shfl_xor(v, o);
  int wave = threadIdx.x >> 6;
  if ((threadIdx.x & 63) == 0) red[wave] = v;
  __syncthreads();
  float r = red[0] + red[1] + red[2] + red[3];
  __syncthreads();
  return r;
}

__global__ __launch_bounds__(256) void k_ln1(
    const float* __restrict__ x, const float* __restrict__ pos,
    const float* __restrict__ P0, const float* __restrict__ P1,
    const float* __restrict__ scale, const float* __restrict__ offset,
    float* __restrict__ outf, __hip_bfloat16* __restrict__ outb) {
  __shared__ float red[4];
  int row = blockIdx.x, tid = threadIdx.x;
  int t = row & (TS - 1), pr = t & (TC - 1);
  size_t base = (size_t)row * TD + tid * 4;
  f32x4 xv = *(const f32x4*)(x + base);
  f32x4 pv = *(const f32x4*)(pos + (size_t)pr * TD + tid * 4);
  f32x4 a0 = *(const f32x4*)(P0 + base);
  f32x4 a1 = *(const f32x4*)(P1 + base);
  xv = xv + pv + a0 + a1;
  float s = xv[0] + xv[1] + xv[2] + xv[3];
  s = block_sum(s, red);
  float mu = s * (1.f / TD);
  float s2 = 0.f;
  for (int j = 0; j < 4; j++) { float dlt = xv[j] - mu; s2 += dlt * dlt; }
  s2 = block_sum(s2, red);
  float rs = rsqrtf(s2 * (1.f / TD) + 1e-5f);
  f32x4 sc = *(const f32x4*)(scale + tid * 4);
  f32x4 of = *(const f32x4*)(offset + tid * 4);
  f32x4 y;
  for (int j = 0; j < 4; j++) y[j] = (xv[j] - mu) * rs * sc[j] + of[j];
  *(f32x4*)(outf + base) = y;
  s16x4 pb;
  for (int j = 0; j < 4; j++) pb[j] = f2bf(y[j]);
  *(s16x4*)((short*)outb + base) = pb;
}

__global__ __launch_bounds__(256) void k_ln2(
    const float* __restrict__ P0, const float* __restrict__ P1,
    const float* __restrict__ R, const float* __restrict__ bias,
    const float* __restrict__ scale, const float* __restrict__ offset,
    float* __restrict__ outf) {
  __shared__ float red[4];
  int row = blockIdx.x, tid = threadIdx.x;
  size_t base = (size_t)row * TD + tid * 4;
  f32x4 a0 = *(const f32x4*)(P0 + base);
  f32x4 a1 = *(const f32x4*)(P1 + base);
  f32x4 rv = *(const f32x4*)(R + base);
  f32x4 bi = *(const f32x4*)(bias + tid * 4);
  f32x4 xv = a0 + a1 + rv + bi;
  float s = xv[0] + xv[1] + xv[2] + xv[3];
  s = block_sum(s, red);
  float mu = s * (1.f / TD);
  float s2 = 0.f;
  for (int j = 0; j < 4; j++) { float dlt = xv[j] - mu; s2 += dlt * dlt; }
  s2 = block_sum(s2, red);
  float rs = rsqrtf(s2 * (1.f / TD) + 1e-5f);
  f32x4 sc = *(const f32x4*)(scale + tid * 4);
  f32x4 of = *(const f32x4*)(offset + tid * 4);
  f32x4 y;
  for (int j = 0; j < 4; j++) y[j] = (xv[j] - mu) * rs * sc[j] + of[j];
  *(f32x4*)(outf + base) = y;
}

// --------------------------------------------------------------------------
extern "C" void kernel_launch(void* const* d_in, const int* in_sizes, int n_in,
                              void* d_out, int out_size, void* d_ws, size_t ws_size,
                              hipStream_t stream) {
  const float* x    = (const float*)d_in[0];
  const float* pos  = (const float*)d_in[2];
  const float* rpe  = (const float*)d_in[3];
  const float* Wq   = (const float*)d_in[4];
  const float* Wk   = (const float*)d_in[5];
  const float* Wv   = (const float*)d_in[6];
  const float* Wo   = (const float*)d_in[7];
  const float* ln1s = (const float*)d_in[8];
  const float* ln1o = (const float*)d_in[9];
  const float* W1   = (const float*)d_in[10];
  const float* b1   = (const float*)d_in[11];
  const float* W2   = (const float*)d_in[12];
  const float* b2   = (const float*)d_in[13];
  const float* ln2s = (const float*)d_in[14];
  const float* ln2o = (const float*)d_in[15];

  char* ws = (char*)d_ws;
  const size_t MB = 1ull << 20;
  __hip_bfloat16* WqkvT = (__hip_bfloat16*)(ws + 0 * MB);   // 6 MB
  __hip_bfloat16* WoT   = (__hip_bfloat16*)(ws + 6 * MB);   // 2 MB
  __hip_bfloat16* W1T   = (__hip_bfloat16*)(ws + 8 * MB);   // 8 MB
  __hip_bfloat16* W2T   = (__hip_bfloat16*)(ws + 16 * MB);  // 8 MB
  __hip_bfloat16* hB    = (__hip_bfloat16*)(ws + 24 * MB);  // 8 MB (dead after QKV)
  __hip_bfloat16* qkv   = (__hip_bfloat16*)(ws + 32 * MB);  // 24 MB (dead after attn)
  __hip_bfloat16* aoB   = (__hip_bfloat16*)(ws + 56 * MB);  // 8 MB (dead after Wo)
  float*          oF2   = (float*)(ws + 64 * MB);           // 32 MB (dead after ln1)
  float*          atF   = (float*)(ws + 96 * MB);           // 16 MB
  __hip_bfloat16* atB   = (__hip_bfloat16*)(ws + 24 * MB);  // 8 MB (aliases hB)
  __hip_bfloat16* ff1   = (__hip_bfloat16*)(ws + 32 * MB);  // 32 MB (aliases qkv+aoB)
  float*          ff2   = (float*)(ws + 64 * MB);           // 32 MB (aliases oF2)
  __hip_bfloat16* vTb   = (__hip_bfloat16*)(ws + 112 * MB); // 8 MB (dead after attn)
  // high-water: 120 MB

  dim3 blk(256), blk5(512);

  k_trans_all<<<12288, blk, 0, stream>>>(Wq, Wk, Wv, Wo, W1, W2,
                                         WqkvT, WoT, W1T, W2T);

  k_addpos<<<(TM * TD / 4 + 255) / 256, blk, 0, stream>>>(x, pos, hB, TM * TD / 4);

  // QKV fused: (4096 x 1024) * (3072 x 1024)^T -> bf16 qkv
  k_gemm8<256, 0><<<dim3(TM / 256, 3072 / 256, 1), blk5, 0, stream>>>(
      hB, WqkvT, qkv, nullptr, TM, 3072, TD, TD, TD);

  k_vtrans<<<dim3(TB * TH, TS / 64), blk, 0, stream>>>(qkv, vTb);
  k_attn<<<TB * TH * (TS / 64), blk, 0, stream>>>(qkv, vTb, rpe, aoB);

  // Wo: BN=128, split-K=2 -> two f32 partials (grid 16x8x2 = 256 blocks)
  k_gemm8<128, 2><<<dim3(TM / 256, TD / 128, 2), blk5, 0, stream>>>(
      aoB, WoT, oF2, nullptr, TM, TD, TD / 2, TD, TD);

  k_ln1<<<TM, blk, 0, stream>>>(x, pos, oF2, oF2 + (size_t)TM * TD, ln1s, ln1o, atF, atB);

  // FFN1: bias+relu -> bf16 (grid 16x16 = 256 blocks)
  k_gemm8<256, 1><<<dim3(TM / 256, TFF / 256, 1), blk5, 0, stream>>>(
      atB, W1T, ff1, b1, TM, TFF, TD, TD, TD);

  // FFN2: BN=128, split-K=2 -> two f32 partials (grid 16x8x2 = 256 blocks)
  k_gemm8<128, 2><<<dim3(TM / 256, TD / 128, 2), blk5, 0, stream>>>(
      ff1, W2T, ff2, nullptr, TM, TD, TFF / 2, TFF, TFF);

  k_ln2<<<TM, blk, 0, stream>>>(ff2, ff2 + (size_t)TM * TD, atF, b2, ln2s, ln2o,
                                (float*)d_out);
}